// Round 4
// baseline (5109.307 us; speedup 1.0000x reference)
//
#include <hip/hip_runtime.h>
#include <math.h>

#define H 512
#define D 512
#define DA 128
#define MAXS 8
#define GH 2048   // 4*H
#define SFIX 512
#define NFIX 768
#define NWG 64    // workgroups (all chains share them)

typedef unsigned short ushort_t;

__device__ __forceinline__ float b2f(ushort_t v) {
  return __uint_as_float(((unsigned int)v) << 16);
}

// ---------------------------------------------------------------------------
// All scratch in module __device__ globals. d_ws untouched.
__device__ int   g_dtype;          // 1 = inputs are bf16, 0 = fp32
// fp32 copies of inputs:
__device__ float g_Wih5[5 * GH * D];
__device__ float g_WihA[GH * DA];
__device__ float g_W1[H * GH];
__device__ float g_We[H * (2 * H + DA)];
__device__ float g_W2[3 * H];
__device__ float g_aemb[3 * DA];
__device__ float g_remb[3 * DA];
__device__ float g_empty[H];
__device__ float g_h0[H];
__device__ float g_c0[H];
__device__ float g_b1[H];
__device__ float g_be[D];
__device__ float g_b2[4];
__device__ float g_bih5[5 * GH];
__device__ float g_bhh5[5 * GH];
__device__ float g_bihA[GH];
__device__ float g_bhhA[GH];
// trajectory index lists:
__device__ int g_bidx_xb[SFIX];
__device__ int g_bsh[NFIX], g_csh[NFIX], g_par[NFIX], g_map_s[NFIX];
__device__ int g_bot[NFIX], g_cot[NFIX];
__device__ int g_bre[NFIX], g_cre[NFIX], g_map_o[NFIX];
__device__ int g_btok[NFIX], g_cide[NFIX], g_redact[NFIX];
__device__ int g_bufp[NFIX], g_stksrc[NFIX], g_outsrc[NFIX];
__device__ int g_counts[16];
// chain synchronization state: per-chain per-WG step tags, 128B apart
__device__ int g_tag[4 * NWG * 32];
// pipeline buffers:
__device__ float g_we[SFIX * D];
__device__ float g_cb[6 * GH];
__device__ float g_Pa[3 * GH];
__device__ float g_XB[SFIX * GH];
__device__ float g_Xso[NFIX * GH];
__device__ float g_E[NFIX * GH];
__device__ float g_Bent[NFIX * 1152];
__device__ float g_ent[NFIX * H];
__device__ float g_Hbuf[(SFIX + 1) * H];
__device__ float g_Sh[NFIX * H], g_Sc[NFIX * H];
__device__ float g_Hos[NFIX * H], g_Has[NFIX * H];
__device__ float g_feat[NFIX * GH];
__device__ float g_t1[NFIX * H];

// device-side selectors (host cannot take addresses of __device__ globals)
__device__ __forceinline__ float* f_conv(int s) {
  switch (s) {
    case 0: return g_Wih5;  case 1: return g_WihA;  case 2: return g_W1;
    case 3: return g_We;    case 4: return g_W2;    case 5: return g_aemb;
    case 6: return g_remb;  case 7: return g_empty; case 8: return g_h0;
    case 9: return g_c0;    case 10: return g_b1;   case 11: return g_be;
    case 12: return g_b2;   case 13: return g_bih5; case 14: return g_bhh5;
    case 15: return g_bihA; case 16: return g_bhhA;
    default: return nullptr;
  }
}
__device__ __forceinline__ const float* f_amat(int s) {
  switch (s) {
    case 0: return g_Wih5; case 1: return g_WihA;
    case 2: return g_We;   case 3: return g_W1;
    default: return nullptr;
  }
}
__device__ __forceinline__ const float* f_src(int s) {
  switch (s) {
    case 0: return g_we;   case 1: return g_ent; case 2: return g_Bent;
    case 3: return g_feat; case 4: return g_aemb;
    default: return nullptr;
  }
}
__device__ __forceinline__ float* f_dst(int s) {
  switch (s) {
    case 0: return g_Pa;  case 1: return g_XB;  case 2: return g_Xso;
    case 3: return g_E;   case 4: return g_ent; case 5: return g_t1;
    default: return nullptr;
  }
}
__device__ __forceinline__ const float* f_bias(int s) {
  switch (s) {
    case 0: return g_cb; case 1: return g_be; case 2: return g_b1;
    default: return nullptr;
  }
}
__device__ __forceinline__ const int* i_arr(int s) {
  switch (s) {
    case 0: return g_bidx_xb;
    case 1: return g_bsh;  case 2: return g_csh;
    case 3: return g_bot;  case 4: return g_cot;
    case 5: return g_bre;  case 6: return g_cre;
    case 7: return g_btok; case 8: return g_cide;
    default: return nullptr;
  }
}

// ---------------------------------------------------------------------------
// MALL-coherent (agent-scope) scalar accesses — compiler-lowered, no asm.
__device__ __forceinline__ float lda_f(const float* p) {
  return __hip_atomic_load(p, __ATOMIC_RELAXED, __HIP_MEMORY_SCOPE_AGENT);
}
__device__ __forceinline__ void sta_f(float* p, float v) {
  __hip_atomic_store(p, v, __ATOMIC_RELAXED, __HIP_MEMORY_SCOPE_AGENT);
}

// ---------------------------------------------------------------------------
// Input-dtype detector: even-indexed ushorts of h0 are valid bf16 exponents
// iff inputs are bf16 (fp32 low-mantissa halves look uniform). 256 samples.
__global__ void k_detect(const void* __restrict__ h0raw) {
  __shared__ int cnt;
  int t = threadIdx.x;
  if (t == 0) cnt = 0;
  __syncthreads();
  const ushort_t* u = (const ushort_t*)h0raw;
  if (t < 256) {
    ushort_t v = u[2 * t];          // in-bounds for both dtypes
    int e = (v >> 7) & 0xFF;
    int ok = (e == 0) || (e >= 96 && e <= 134);
    atomicAdd(&cnt, ok);
  }
  __syncthreads();
  if (t == 0) g_dtype = (cnt >= 160) ? 1 : 0;
}

// ---------------------------------------------------------------------------
__global__ void k_b2f(const void* __restrict__ src, int dsel, int n) {
  float* dst = f_conv(dsel);
  int bf = g_dtype;
  int i = blockIdx.x * blockDim.x + threadIdx.x;
  int stride = gridDim.x * blockDim.x;
  if (bf) {
    const ushort_t* s = (const ushort_t*)src;
    for (; i < n; i += stride) dst[i] = b2f(s[i]);
  } else {
    const float* s = (const float*)src;
    for (; i < n; i += stride) dst[i] = s[i];
  }
}

// ---------------------------------------------------------------------------
__global__ void k_makewe(const int* __restrict__ sent, const void* __restrict__ wemb, int S) {
  int i = blockIdx.x;
  int tok = sent[i];
  if (tok < 0) tok = 0;
  float* dst = g_we + (size_t)i * D;
  if (g_dtype) {
    const ushort_t* src = (const ushort_t*)wemb + (size_t)tok * D;
    for (int j = threadIdx.x; j < D; j += blockDim.x) dst[j] = b2f(src[j]);
  } else {
    const float* src = (const float*)wemb + (size_t)tok * D;
    for (int j = threadIdx.x; j < D; j += blockDim.x) dst[j] = src[j];
  }
}

// ---------------------------------------------------------------------------
// Sequential int-only simulation of the transition system.
__global__ void k_traj(const int* __restrict__ actions, int NACT, int S) {
  int tid = threadIdx.x;
  for (int t = tid; t < NACT; t += blockDim.x) {
    g_bsh[t] = -1; g_csh[t] = -1; g_par[t] = -1; g_map_s[t] = 0;
    g_bot[t] = -1; g_cot[t] = -1;
    g_bre[t] = -1; g_cre[t] = -1; g_map_o[t] = 0;
    g_btok[t] = -1; g_cide[t] = -1; g_redact[t] = 0;
  }
  for (int t = tid; t < S; t += blockDim.x) g_bidx_xb[t] = S - 1 - t;
  // reset chain tags every launch (graph replays re-run this)
  for (int t = tid; t < 4 * NWG * 32; t += blockDim.x) g_tag[t] = 0;
  __syncthreads();
  if (tid != 0) return;

  int pb = S, ps = 0, po = 0, nsh = 0, nred = 0;
  int slot_id[MAXS + 1], slot_tok[MAXS + 1];
  for (int s = 0; s <= MAXS; s++) { slot_id[s] = -2; slot_tok[s] = -1; }

  for (int t = 0; t < NACT; t++) {
    int a = actions[t];
    g_bufp[t] = pb;
    int rs = (ps < MAXS) ? ps : MAXS;
    g_stksrc[t] = (ps > 0) ? slot_id[rs] : -1;  // -1 empty, -2 zeros, j push id
    g_outsrc[t] = po;
    int tb = S - pb; if (tb < 0) tb = 0; if (tb > S - 1) tb = S - 1;
    if (a == 0) {            // SHIFT
      g_par[nsh] = (ps == 0) ? -1 : slot_id[rs];
      g_map_s[nsh] = t;
      g_bsh[t] = tb; g_csh[t] = t;
      int w = (ps + 1 < MAXS) ? ps + 1 : MAXS;
      slot_id[w] = nsh; slot_tok[w] = tb;
      nsh++; ps++; pb--;
    } else if (a == 1) {     // OUT
      g_bot[t] = tb; g_cot[t] = t;
      g_map_o[po] = t;
      po++; pb--;
    } else {                 // REDUCE
      g_btok[nred] = (ps > 0) ? slot_tok[rs] : -1;
      g_cide[nred] = nred; g_redact[nred] = (a < 0) ? 0 : ((a > 2) ? 2 : a);
      g_bre[t] = nred; g_cre[t] = t;
      g_map_o[po] = t;
      po++; nred++;
      ps = (ps > 0) ? ps - 1 : 0;
    }
    if (pb < 0) pb = 0;
  }
  g_counts[0] = nsh; g_counts[1] = po; g_counts[2] = nred;
}

// ---------------------------------------------------------------------------
// cb[c] = bih+bhh (+ Whh@h0 for entity cells, raw-dtype read)
__global__ void k_cbias(const void* __restrict__ Whh5raw) {
  int idx = blockIdx.x * blockDim.x + threadIdx.x;
  if (idx >= 6 * GH) return;
  int c = idx >> 11, m = idx & (GH - 1);
  float v;
  if (c < 5) v = g_bih5[c * GH + m] + g_bhh5[c * GH + m];
  else       v = g_bihA[m] + g_bhhA[m];
  if (c == 3 || c == 4) {
    size_t base = ((size_t)c * GH + m) * H;
    float acc = 0.f;
    if (g_dtype) {
      const ushort_t* w = (const ushort_t*)Whh5raw;
      for (int k = 0; k < H; k++) acc += b2f(w[base + k]) * g_h0[k];
    } else {
      const float* w = (const float*)Whh5raw;
      for (int k = 0; k < H; k++) acc += w[base + k] * g_h0[k];
    }
    v += acc;
  }
  g_cb[idx] = v;
}

// ---------------------------------------------------------------------------
// Gathered GEMM over selector-resolved fp32 scratch:
// C[cidx[n]] = act( A(MxK) @ Brow(n) + bias )
__global__ __launch_bounds__(256) void k_gemm(
    int asel, int aoff, int M, int K,
    int bsel, int bstride,
    int bidx_sel, int cidx_sel, int N,
    int bias_sel, int cb_off, int csel, int act) {
  const float* A = f_amat(asel) + aoff;
  const float* Bsrc = f_src(bsel);
  const float* bias = f_bias(bias_sel) + cb_off;
  const int* bidx = i_arr(bidx_sel);
  const int* cidx = i_arr(cidx_sel);
  float* C = f_dst(csel);

  int mblk = blockIdx.x * 64, nblk = blockIdx.y * 64;
  __shared__ int rowc[64];
  __shared__ float As[16][68];
  __shared__ float Bs[16][68];
  int tid = threadIdx.x;
  if (tid < 64) {
    int n = nblk + tid;
    int cr = -1;
    if (n < N) cr = cidx ? cidx[n] : n;
    if (cr >= NFIX) cr = -1;
    rowc[tid] = cr;
  }
  __syncthreads();
  bool any = false;
  for (int i = 0; i < 64; i++) if (rowc[i] >= 0) { any = true; break; }
  if (!any) return;

  float acc[4][4] = {};
  int tx = tid & 15, ty = tid >> 4;
  int mm = tid >> 2, kq = (tid & 3) * 4;
  int n = nblk + mm;
  const float* bp = nullptr;
  if (n < N) {
    if (bidx) { int bi = bidx[n]; if (bi >= 0 && bi < NFIX) bp = Bsrc + (size_t)bi * bstride; }
    else bp = Bsrc + (size_t)n * bstride;
  }
  const float* ap = A + (size_t)(mblk + mm) * K + kq;

  for (int k0 = 0; k0 < K; k0 += 16) {
    float4 av = *(const float4*)(ap + k0);
    float4 bv = bp ? *(const float4*)(bp + k0 + kq) : make_float4(0.f, 0.f, 0.f, 0.f);
    As[kq + 0][mm] = av.x; As[kq + 1][mm] = av.y; As[kq + 2][mm] = av.z; As[kq + 3][mm] = av.w;
    Bs[kq + 0][mm] = bv.x; Bs[kq + 1][mm] = bv.y; Bs[kq + 2][mm] = bv.z; Bs[kq + 3][mm] = bv.w;
    __syncthreads();
#pragma unroll
    for (int kk = 0; kk < 16; kk++) {
      float a0 = As[kk][tx * 4 + 0], a1 = As[kk][tx * 4 + 1];
      float a2 = As[kk][tx * 4 + 2], a3 = As[kk][tx * 4 + 3];
      float b0 = Bs[kk][ty * 4 + 0], b1 = Bs[kk][ty * 4 + 1];
      float b2 = Bs[kk][ty * 4 + 2], b3 = Bs[kk][ty * 4 + 3];
      acc[0][0] = fmaf(b0, a0, acc[0][0]); acc[0][1] = fmaf(b0, a1, acc[0][1]);
      acc[0][2] = fmaf(b0, a2, acc[0][2]); acc[0][3] = fmaf(b0, a3, acc[0][3]);
      acc[1][0] = fmaf(b1, a0, acc[1][0]); acc[1][1] = fmaf(b1, a1, acc[1][1]);
      acc[1][2] = fmaf(b1, a2, acc[1][2]); acc[1][3] = fmaf(b1, a3, acc[1][3]);
      acc[2][0] = fmaf(b2, a0, acc[2][0]); acc[2][1] = fmaf(b2, a1, acc[2][1]);
      acc[2][2] = fmaf(b2, a2, acc[2][2]); acc[2][3] = fmaf(b2, a3, acc[2][3]);
      acc[3][0] = fmaf(b3, a0, acc[3][0]); acc[3][1] = fmaf(b3, a1, acc[3][1]);
      acc[3][2] = fmaf(b3, a2, acc[3][2]); acc[3][3] = fmaf(b3, a3, acc[3][3]);
    }
    __syncthreads();
  }
#pragma unroll
  for (int i = 0; i < 4; i++) {
    int crow = rowc[ty * 4 + i];
    if (crow < 0) continue;
    int mj = mblk + tx * 4;
    float4 v;
    v.x = acc[i][0] + bias[mj + 0];
    v.y = acc[i][1] + bias[mj + 1];
    v.z = acc[i][2] + bias[mj + 2];
    v.w = acc[i][3] + bias[mj + 3];
    if (act) { v.x = tanhf(v.x); v.y = tanhf(v.y); v.z = tanhf(v.z); v.w = tanhf(v.w); }
    *(float4*)(C + (size_t)crow * M + mj) = v;
  }
}

// ---------------------------------------------------------------------------
// Entity epilogues (two passes over g_E).
__global__ void k_entityA() {
  int r = blockIdx.x;
  if (g_cide[r] < 0) return;
  int j = threadIdx.x;  // 512
  const float* z = g_E + (size_t)r * GH;
  float zi = z[j], zf = z[j + 512], zg = z[j + 1024], zo = z[j + 1536];
  float i_ = 1.f / (1.f + expf(-zi));
  float f_ = 1.f / (1.f + expf(-zf));
  float o_ = 1.f / (1.f + expf(-zo));
  float c2 = f_ * g_c0[j] + i_ * tanhf(zg);
  g_Bent[(size_t)r * 1152 + j] = o_ * tanhf(c2);
  if (j < DA) g_Bent[(size_t)r * 1152 + 1024 + j] = g_remb[g_redact[r] * DA + j];
}
__global__ void k_entityB() {
  int r = blockIdx.x;
  if (g_cide[r] < 0) return;
  int j = threadIdx.x;  // 512
  const float* z = g_E + (size_t)r * GH;
  float zi = z[j], zf = z[j + 512], zg = z[j + 1024], zo = z[j + 1536];
  float i_ = 1.f / (1.f + expf(-zi));
  float f_ = 1.f / (1.f + expf(-zf));
  float o_ = 1.f / (1.f + expf(-zo));
  float c2 = f_ * g_c0[j] + i_ * tanhf(zg);
  g_Bent[(size_t)r * 1152 + 512 + j] = o_ * tanhf(c2);
}

// ---------------------------------------------------------------------------
// INTERLEAVED quarter-step chain engine.
//
// 64 WGs x 512 threads; every WG owns h-outputs [w*8, w*8+8) of ALL FOUR
// chains (32 z-rows per chain; thread t = (row r=t&31, k-chunk kc=t>>5 of
// 32 k); weights 8 float4 per chain = 128 VGPR total, loaded once from raw
// Whh). A superstep runs one quarter per active chain (chain 2 offset by
// ns3-ns2 so >=2 chains are always in flight). Latency hiding:
//   - tag publish DEFERRED to the next quarter's entry (drain overlaps
//     compute; wave 0 never issues fresh preloads, so its release-waitcnt
//     has nothing young to wait on);
//   - prev-h PRELOADED into registers (waves 1-7; wave 1 double-loads
//     wave 0's slots) via one-shot polls at quarter tails, 1-3 quarters
//     before consumption; slow spin path only on a miss.
// Deadlock-free: every spin waits on peers reaching a strictly earlier
// quarter index; pending tags are published before any spin.
template <int C>
__device__ __forceinline__ const float* prevh_ptr(int s) {
  if constexpr (C == 0) {
    return (s == 0) ? g_h0 : g_Hbuf + (size_t)s * H;   // outH0 + (s-1)*H
  } else if constexpr (C == 2) {
    return (s == 0) ? g_h0 : g_Hos + (size_t)(s - 1) * H;
  } else if constexpr (C == 3) {
    return (s == 0) ? g_h0 : g_Has + (size_t)(s - 1) * H;
  } else {
    int p = g_par[s];
    if (p == -1) return g_h0;
    if (p < -1) return nullptr;                        // zeros
    if (p >= NFIX) p = NFIX - 1;
    return g_Sh + (size_t)p * H;
  }
}
template <int C>
__device__ __forceinline__ const float* xrow_ptr(int s, const int* acts) {
  if constexpr (C == 0) {
    return g_XB + (size_t)s * GH;
  } else if constexpr (C == 1) {
    int mm = g_map_s[s]; if (mm < 0) mm = 0; if (mm >= NFIX) mm = NFIX - 1;
    return g_Xso + (size_t)mm * GH;
  } else if constexpr (C == 2) {
    int mm = g_map_o[s]; if (mm < 0) mm = 0; if (mm >= NFIX) mm = NFIX - 1;
    return g_Xso + (size_t)mm * GH;
  } else {
    int a = acts[s]; if (a < 0) a = 0; if (a > 2) a = 2;
    return g_Pa + (size_t)a * GH;
  }
}
template <int C>
__device__ __forceinline__ float* outh_ptr() {
  if constexpr (C == 0) return g_Hbuf + H;
  else if constexpr (C == 1) return g_Sh;
  else if constexpr (C == 2) return g_Hos;
  else return g_Has;
}

template <int C>
__device__ __forceinline__ void quarter_step(
    int t, int w, int j0, int kc, int r, int kb,
    const int* __restrict__ acts,
    const float4 (&wvc)[8],
    float (&hreg)[4], float (&hregB)[4], float (&creg)[4],
    int (&dc)[4], int (&pre)[4], const int (&nsv)[4],
    int& pendc, int& pendv,
    float* hsh, float (*psh)[32], float* zrow, int* rd) {
  const int s = dc[C];

  // (1) publish previous quarter's tag (deferred release; drain overlaps)
  if (t == 0 && pendv > 0) {
    __hip_atomic_store(&g_tag[(pendc * NWG + w) * 32], pendv,
                       __ATOMIC_RELEASE, __HIP_MEMORY_SCOPE_AGENT);
  }

  // (2) prev-h -> LDS (fast: preloaded regs; slow: spin + direct load)
  if (pre[C]) {
    if (t >= 64) hsh[t] = hreg[C];
    if (t >= 64 && t < 128) hsh[t - 64] = hregB[C];
  } else {
    if (s > 0 && t < 64) {
      for (;;) {
        int tg = __hip_atomic_load(&g_tag[(C * NWG + t) * 32],
                                   __ATOMIC_RELAXED, __HIP_MEMORY_SCOPE_AGENT);
        if (__all(tg >= s)) break;
        __builtin_amdgcn_s_sleep(1);
      }
    }
    __syncthreads();
    const float* hp = prevh_ptr<C>(s);
    hsh[t] = hp ? lda_f(hp + t) : 0.f;
  }

  // (3) prefetch x (rows 0..31) and chain-1 cprev (gate lanes)
  float xv = 0.f;
  {
    const float* xrow = xrow_ptr<C>(s, acts);
    if (t < 32) xv = xrow[((t >> 3) * 512) + j0 + (t & 7)];
  }
  float cpre = 0.f;
  if constexpr (C == 1) {
    if (t < 8) {
      int p = g_par[s];
      if (p == -1) cpre = g_c0[j0 + t];
      else if (p >= 0) {
        int pp = (p < NFIX) ? p : NFIX - 1;
        cpre = lda_f(&g_Sc[(size_t)pp * H + j0 + t]);
      }
    }
  }
  __syncthreads();                       // B1: hsh ready

  // (4) matvec partials: 8x(LDS b128 broadcast + 4 FMA)
  float4 acc = make_float4(0.f, 0.f, 0.f, 0.f);
#pragma unroll
  for (int i = 0; i < 8; i++) {
    float4 hv = *(const float4*)&hsh[kb + 4 * i];
    acc.x = fmaf(wvc[i].x, hv.x, acc.x);
    acc.y = fmaf(wvc[i].y, hv.y, acc.y);
    acc.z = fmaf(wvc[i].z, hv.z, acc.z);
    acc.w = fmaf(wvc[i].w, hv.w, acc.w);
  }
  psh[kc][r] = (acc.x + acc.y) + (acc.z + acc.w);
  __syncthreads();                       // B2: partials ready

  // (5) reduce (wave-0 lanes 0..31) || one-shot preload polls (waves 1..4)
  if (t < 32) {
    float z = xv;
#pragma unroll
    for (int q = 0; q < 16; q++) z += psh[q][t];
    zrow[t] = z;
  }
#pragma unroll
  for (int cc = 0; cc < 4; cc++) {
    if (cc == C) continue;
    if ((t >> 6) == 1 + cc) {
      int ok = 0;
      if (!pre[cc] && dc[cc] < nsv[cc]) {
        if (dc[cc] == 0) ok = 1;
        else {
          int tg = __hip_atomic_load(&g_tag[(cc * NWG + (t & 63)) * 32],
                                     __ATOMIC_RELAXED, __HIP_MEMORY_SCOPE_AGENT);
          ok = __all(tg >= dc[cc]) ? 1 : 0;
        }
      }
      if ((t & 63) == 0) rd[cc] = ok;
    }
  }
  __syncthreads();                       // B3: zrow + rd ready

  // (6) gates + state + h/c store (lanes 0..7); preload issues (waves 1+)
  if (t < 8) {
    float zi = zrow[t], zf = zrow[8 + t], zg = zrow[16 + t], zo = zrow[24 + t];
    float i_ = 1.f / (1.f + expf(-zi));
    float f_ = 1.f / (1.f + expf(-zf));
    float o_ = 1.f / (1.f + expf(-zo));
    float cp = (C == 1) ? cpre : creg[C];
    float c2 = f_ * cp + i_ * tanhf(zg);
    float hn = o_ * tanhf(c2);
    if constexpr (C == 1) sta_f(&g_Sc[(size_t)s * H + j0 + t], c2);
    else creg[C] = c2;
    sta_f(&outh_ptr<C>()[(size_t)s * H + j0 + t], hn);
  }
#pragma unroll
  for (int cc = 0; cc < 4; cc++) {
    if (cc == C) continue;
    if (rd[cc]) {
      const float* hp;
      if (cc == 0)      hp = prevh_ptr<0>(dc[0]);
      else if (cc == 1) hp = prevh_ptr<1>(dc[1]);
      else if (cc == 2) hp = prevh_ptr<2>(dc[2]);
      else              hp = prevh_ptr<3>(dc[3]);
      if (t >= 64)            hreg[cc]  = hp ? lda_f(hp + t) : 0.f;
      if (t >= 64 && t < 128) hregB[cc] = hp ? lda_f(hp + (t - 64)) : 0.f;
      pre[cc] = 1;
    }
  }
  dc[C] = s + 1;
  pre[C] = 0;
  pendc = C; pendv = s + 1;
}

__global__ __launch_bounds__(512, 1) void k_chain_q(
    const int* __restrict__ acts,
    const void* __restrict__ Whh5raw, const void* __restrict__ WhhAraw,
    int S, int NACT) {
  const int w = blockIdx.x;              // 0..63
  const int t = threadIdx.x;             // 0..511
  const int r = t & 31;                  // row-local
  const int kc = t >> 5;                 // k-chunk (32 k each)
  const int j0 = w * 8;
  const int m = ((r >> 3) * 512) + j0 + (r & 7);   // z-row
  const int kb = kc * 32;

  int nsv[4];
  nsv[0] = S;
  nsv[1] = g_counts[0]; if (nsv[1] < 0) nsv[1] = 0; if (nsv[1] > NFIX) nsv[1] = NFIX;
  nsv[2] = g_counts[1]; if (nsv[2] < 0) nsv[2] = 0; if (nsv[2] > NFIX) nsv[2] = NFIX;
  nsv[3] = NACT;
  const int off2 = (nsv[3] > nsv[2]) ? (nsv[3] - nsv[2]) : 0;
  int maxss = nsv[0];
  if (nsv[1] > maxss) maxss = nsv[1];
  if (nsv[3] > maxss) maxss = nsv[3];
  if (off2 + nsv[2] > maxss) maxss = off2 + nsv[2];

  // one-time: weight slices -> registers (raw dtype; no transpose pass)
  float4 wv0[8], wv1[8], wv2[8], wv3[8];
  if (g_dtype) {
    const ushort_t* b5 = (const ushort_t*)Whh5raw;
    const ushort_t* ba = (const ushort_t*)WhhAraw;
#pragma unroll
    for (int i = 0; i < 8; i++) {
      ushort4 u;
      u = *(const ushort4*)(b5 + ((size_t)0 * GH + m) * H + kb + 4 * i);
      wv0[i] = make_float4(b2f(u.x), b2f(u.y), b2f(u.z), b2f(u.w));
      u = *(const ushort4*)(b5 + ((size_t)1 * GH + m) * H + kb + 4 * i);
      wv1[i] = make_float4(b2f(u.x), b2f(u.y), b2f(u.z), b2f(u.w));
      u = *(const ushort4*)(b5 + ((size_t)2 * GH + m) * H + kb + 4 * i);
      wv2[i] = make_float4(b2f(u.x), b2f(u.y), b2f(u.z), b2f(u.w));
      u = *(const ushort4*)(ba + (size_t)m * H + kb + 4 * i);
      wv3[i] = make_float4(b2f(u.x), b2f(u.y), b2f(u.z), b2f(u.w));
    }
  } else {
    const float* b5 = (const float*)Whh5raw;
    const float* ba = (const float*)WhhAraw;
#pragma unroll
    for (int i = 0; i < 8; i++) {
      wv0[i] = *(const float4*)(b5 + ((size_t)0 * GH + m) * H + kb + 4 * i);
      wv1[i] = *(const float4*)(b5 + ((size_t)1 * GH + m) * H + kb + 4 * i);
      wv2[i] = *(const float4*)(b5 + ((size_t)2 * GH + m) * H + kb + 4 * i);
      wv3[i] = *(const float4*)(ba + (size_t)m * H + kb + 4 * i);
    }
  }

  float creg[4] = {0.f, 0.f, 0.f, 0.f};
  if (t < 8) {
    float cz = g_c0[j0 + t];
    creg[0] = cz; creg[2] = cz; creg[3] = cz;   // chain 1 uses g_Sc/par
  }

  __shared__ __align__(16) float hsh[512];
  __shared__ float psh[16][32];
  __shared__ float zrow[32];
  __shared__ int rd[4];

  float hreg[4] = {0.f, 0.f, 0.f, 0.f};
  float hregB[4] = {0.f, 0.f, 0.f, 0.f};
  int dc[4] = {0, 0, 0, 0};
  int pre[4] = {0, 0, 0, 0};
  int pendc = 0, pendv = 0;

  for (int ss = 0; ss < maxss; ss++) {
    if (dc[0] < nsv[0])
      quarter_step<0>(t, w, j0, kc, r, kb, acts, wv0, hreg, hregB, creg,
                      dc, pre, nsv, pendc, pendv, hsh, psh, zrow, rd);
    if (dc[1] < nsv[1])
      quarter_step<1>(t, w, j0, kc, r, kb, acts, wv1, hreg, hregB, creg,
                      dc, pre, nsv, pendc, pendv, hsh, psh, zrow, rd);
    if (ss >= off2 && dc[2] < nsv[2])
      quarter_step<2>(t, w, j0, kc, r, kb, acts, wv2, hreg, hregB, creg,
                      dc, pre, nsv, pendc, pendv, hsh, psh, zrow, rd);
    if (dc[3] < nsv[3])
      quarter_step<3>(t, w, j0, kc, r, kb, acts, wv3, hreg, hregB, creg,
                      dc, pre, nsv, pendc, pendv, hsh, psh, zrow, rd);
  }
}

// ---------------------------------------------------------------------------
__global__ void k_feat() {
  int t = blockIdx.x;
  int j = threadIdx.x;  // 512
  float* f = g_feat + (size_t)t * GH;
  int s = g_stksrc[t]; if (s >= NFIX) s = NFIX - 1;
  f[j] = (s == -1) ? g_empty[j] : ((s < 0) ? 0.f : g_Sh[(size_t)s * H + j]);
  int p = g_bufp[t]; if (p > SFIX) p = SFIX;
  f[H + j] = (p > 0) ? g_Hbuf[(size_t)p * H + j] : g_empty[j];
  int k = g_outsrc[t]; if (k > NFIX) k = NFIX;
  f[2 * H + j] = (k > 0) ? g_Hos[(size_t)(k - 1) * H + j] : g_empty[j];
  f[3 * H + j] = (t > 0) ? g_Has[(size_t)(t - 1) * H + j] : g_empty[j];
}

// ---------------------------------------------------------------------------
__global__ void k_final(const int* __restrict__ actions, void* __restrict__ out) {
  int t = blockIdx.x;
  int lane = threadIdx.x;  // 64
  const float* tv = g_t1 + (size_t)t * H;
  float a0 = 0.f, a1 = 0.f, a2 = 0.f;
  for (int j = lane; j < H; j += 64) {
    float v = tv[j];
    a0 += g_W2[j] * v; a1 += g_W2[H + j] * v; a2 += g_W2[2 * H + j] * v;
  }
  for (int off = 32; off; off >>= 1) {
    a0 += __shfl_down(a0, off);
    a1 += __shfl_down(a1, off);
    a2 += __shfl_down(a2, off);
  }
  if (lane == 0) {
    a0 += g_b2[0]; a1 += g_b2[1]; a2 += g_b2[2];
    float m = fmaxf(a0, fmaxf(a1, a2));
    float lse = m + logf(expf(a0 - m) + expf(a1 - m) + expf(a2 - m));
    int a = actions[t];
    float la = (a <= 0) ? a0 : ((a == 1) ? a1 : a2);
    float v = lse - la;
    if (g_dtype) {
      unsigned int b = __float_as_uint(v);
      b += 0x7FFFu + ((b >> 16) & 1u);     // RNE to bf16
      ((ushort_t*)out)[t] = (ushort_t)(b >> 16);
    } else {
      ((float*)out)[t] = v;
    }
  }
}

// ---------------------------------------------------------------------------
extern "C" void kernel_launch(void* const* d_in, const int* in_sizes, int n_in,
                              void* d_out, int out_size, void* d_ws, size_t ws_size,
                              hipStream_t stream) {
  const int* sent   = (const int*)d_in[0];
  const int* actions= (const int*)d_in[1];
  const void* wemb  = d_in[2];
  const void* aemb  = d_in[3];
  const void* remb  = d_in[4];
  const void* empty = d_in[5];
  const void* h0    = d_in[6];
  const void* c0    = d_in[7];
  const void* Wih5  = d_in[8];
  const void* Whh5  = d_in[9];
  const void* bih5  = d_in[10];
  const void* bhh5  = d_in[11];
  const void* Wih_a = d_in[12];
  const void* Whh_a = d_in[13];
  const void* bih_a = d_in[14];
  const void* bhh_a = d_in[15];
  const void* W1    = d_in[16];
  const void* b1    = d_in[17];
  const void* W2    = d_in[18];
  const void* b2    = d_in[19];
  const void* We    = d_in[20];
  const void* be    = d_in[21];
  int S = in_sizes[0];    // 512
  int NACT = in_sizes[1]; // 768
  if (S > SFIX) S = SFIX;
  if (NACT > NFIX) NACT = NFIX;
  (void)n_in; (void)out_size; (void)d_ws; (void)ws_size;

  k_detect<<<1, 256, 0, stream>>>(h0);

  auto conv = [&](const void* src, int dsel, int n) {
    int blocks = (n + 255) / 256; if (blocks > 1024) blocks = 1024;
    k_b2f<<<blocks, 256, 0, stream>>>(src, dsel, n);
  };
  conv(Wih5, 0, 5 * GH * D);
  conv(Wih_a, 1, GH * DA);
  conv(W1, 2, H * GH);
  conv(We, 3, H * (2 * H + DA));
  conv(W2, 4, 3 * H);
  conv(aemb, 5, 3 * DA);
  conv(remb, 6, 3 * DA);
  conv(empty, 7, H);
  conv(h0, 8, H);
  conv(c0, 9, H);
  conv(b1, 10, H);
  conv(be, 11, D);
  conv(b2, 12, 3);
  conv(bih5, 13, 5 * GH);
  conv(bhh5, 14, 5 * GH);
  conv(bih_a, 15, GH);
  conv(bhh_a, 16, GH);

  k_makewe<<<S, 256, 0, stream>>>(sent, wemb, S);
  k_traj<<<1, 64, 0, stream>>>(actions, NACT, S);
  k_cbias<<<(6 * GH + 255) / 256, 256, 0, stream>>>(Whh5);

  dim3 gPa(GH / 64, 1);
  dim3 gXB(GH / 64, (S + 63) / 64);
  dim3 gN(GH / 64, (NACT + 63) / 64);
  dim3 gH(H / 64, (NACT + 63) / 64);
  // Pa[a] = WihA @ aemb[a] + cb5  (3 distinct actions)
  k_gemm<<<gPa, 256, 0, stream>>>(1, 0, GH, DA, 4, DA, -1, -1, 3, 0, 5 * GH, 0, 0);
  // XB = Wih0 @ we[reversed] + cb0
  k_gemm<<<gXB, 256, 0, stream>>>(0, 0, GH, D, 0, D, 0, -1, S, 0, 0, 1, 0);
  // Xso[t] SHIFT: Wih1 @ we[tok] + cb1
  k_gemm<<<gN, 256, 0, stream>>>(0, 1 * GH * D, GH, D, 0, D, 1, 2, NACT, 0, GH, 2, 0);
  // Xso[t] OUT: Wih2 @ we[tok] + cb2
  k_gemm<<<gN, 256, 0, stream>>>(0, 2 * GH * D, GH, D, 0, D, 3, 4, NACT, 0, 2 * GH, 2, 0);
  // E = Wih3 @ we[reduce tok] + cb3 ; entity-fwd -> Bent[:, :512]
  k_gemm<<<gN, 256, 0, stream>>>(0, 3 * GH * D, GH, D, 0, D, 7, 8, NACT, 0, 3 * GH, 3, 0);
  k_entityA<<<NACT, 512, 0, stream>>>();
  // E = Wih4 @ we[reduce tok] + cb4 ; entity-bwd -> Bent[:, 512:1024]
  k_gemm<<<gN, 256, 0, stream>>>(0, 4 * GH * D, GH, D, 0, D, 7, 8, NACT, 0, 4 * GH, 3, 0);
  k_entityB<<<NACT, 512, 0, stream>>>();
  // ent = tanh(We @ Bent + be)
  k_gemm<<<gH, 256, 0, stream>>>(2, 0, H, 2 * H + DA, 2, 1152, -1, 8, NACT, 1, 0, 4, 1);
  // Xso[t] REDUCE: Wih2 @ ent[r] + cb2
  k_gemm<<<gN, 256, 0, stream>>>(0, 2 * GH * D, GH, D, 1, H, 5, 6, NACT, 0, 2 * GH, 2, 0);
  // Four LSTM recurrences, interleaved quarter-steps on 64 WGs.
  k_chain_q<<<NWG, 512, 0, stream>>>(actions, Whh5, Whh_a, S, NACT);
  k_feat<<<NACT, 512, 0, stream>>>();
  // t1 = tanh(W1 @ feat + b1)
  k_gemm<<<gH, 256, 0, stream>>>(3, 0, H, GH, 3, GH, -1, -1, NACT, 2, 0, 5, 1);
  k_final<<<NACT, 64, 0, stream>>>(actions, d_out);
}

// Round 5
// 2233.071 us; speedup vs baseline: 2.2880x; 2.2880x over previous
//
#include <hip/hip_runtime.h>
#include <math.h>

#define H 512
#define D 512
#define DA 128
#define MAXS 8
#define GH 2048   // 4*H
#define SFIX 512
#define NFIX 768
#define WPC 16    // workgroups per chain
#define CANARY 0x7FC00BADu   // quiet-NaN poison: unreachable by LSTM outputs

typedef unsigned short ushort_t;

__device__ __forceinline__ float b2f(ushort_t v) {
  return __uint_as_float(((unsigned int)v) << 16);
}

// ---------------------------------------------------------------------------
// All scratch in module __device__ globals. d_ws untouched.
__device__ int   g_dtype;          // 1 = inputs are bf16, 0 = fp32
// fp32 copies of inputs:
__device__ float g_Wih5[5 * GH * D];
__device__ float g_WihA[GH * DA];
__device__ float g_W1[H * GH];
__device__ float g_We[H * (2 * H + DA)];
__device__ float g_W2[3 * H];
__device__ float g_aemb[3 * DA];
__device__ float g_remb[3 * DA];
__device__ float g_empty[H];
__device__ float g_h0[H];
__device__ float g_c0[H];
__device__ float g_b1[H];
__device__ float g_be[D];
__device__ float g_b2[4];
__device__ float g_bih5[5 * GH];
__device__ float g_bhh5[5 * GH];
__device__ float g_bihA[GH];
__device__ float g_bhhA[GH];
// trajectory index lists:
__device__ int g_bidx_xb[SFIX];
__device__ int g_bsh[NFIX], g_csh[NFIX], g_par[NFIX], g_map_s[NFIX];
__device__ int g_bot[NFIX], g_cot[NFIX];
__device__ int g_bre[NFIX], g_cre[NFIX], g_map_o[NFIX];
__device__ int g_btok[NFIX], g_cide[NFIX], g_redact[NFIX];
__device__ int g_bufp[NFIX], g_stksrc[NFIX], g_outsrc[NFIX];
__device__ int g_counts[16];
// pipeline buffers:
__device__ float g_we[SFIX * D];
__device__ float g_cb[6 * GH];
__device__ float g_Pa[3 * GH];
__device__ float g_XB[SFIX * GH];
__device__ float g_Xso[NFIX * GH];
__device__ float g_E[NFIX * GH];
__device__ float g_Bent[NFIX * 1152];
__device__ float g_ent[NFIX * H];
__device__ float g_Hbuf[(SFIX + 1) * H];
__device__ float g_Sh[NFIX * H], g_Sc[NFIX * H];
__device__ float g_Hos[NFIX * H], g_Has[NFIX * H];
__device__ float g_feat[NFIX * GH];
__device__ float g_t1[NFIX * H];

// device-side selectors (host cannot take addresses of __device__ globals)
__device__ __forceinline__ float* f_conv(int s) {
  switch (s) {
    case 0: return g_Wih5;  case 1: return g_WihA;  case 2: return g_W1;
    case 3: return g_We;    case 4: return g_W2;    case 5: return g_aemb;
    case 6: return g_remb;  case 7: return g_empty; case 8: return g_h0;
    case 9: return g_c0;    case 10: return g_b1;   case 11: return g_be;
    case 12: return g_b2;   case 13: return g_bih5; case 14: return g_bhh5;
    case 15: return g_bihA; case 16: return g_bhhA;
    default: return nullptr;
  }
}
__device__ __forceinline__ const float* f_amat(int s) {
  switch (s) {
    case 0: return g_Wih5; case 1: return g_WihA;
    case 2: return g_We;   case 3: return g_W1;
    default: return nullptr;
  }
}
__device__ __forceinline__ const float* f_src(int s) {
  switch (s) {
    case 0: return g_we;   case 1: return g_ent; case 2: return g_Bent;
    case 3: return g_feat; case 4: return g_aemb;
    default: return nullptr;
  }
}
__device__ __forceinline__ float* f_dst(int s) {
  switch (s) {
    case 0: return g_Pa;  case 1: return g_XB;  case 2: return g_Xso;
    case 3: return g_E;   case 4: return g_ent; case 5: return g_t1;
    default: return nullptr;
  }
}
__device__ __forceinline__ const float* f_bias(int s) {
  switch (s) {
    case 0: return g_cb; case 1: return g_be; case 2: return g_b1;
    default: return nullptr;
  }
}
__device__ __forceinline__ const int* i_arr(int s) {
  switch (s) {
    case 0: return g_bidx_xb;
    case 1: return g_bsh;  case 2: return g_csh;
    case 3: return g_bot;  case 4: return g_cot;
    case 5: return g_bre;  case 6: return g_cre;
    case 7: return g_btok; case 8: return g_cide;
    default: return nullptr;
  }
}

// ---------------------------------------------------------------------------
// MALL-coherent (agent-scope) scalar accesses — compiler-lowered, no asm.
__device__ __forceinline__ float lda_f(const float* p) {
  return __hip_atomic_load(p, __ATOMIC_RELAXED, __HIP_MEMORY_SCOPE_AGENT);
}
__device__ __forceinline__ void sta_f(float* p, float v) {
  __hip_atomic_store(p, v, __ATOMIC_RELAXED, __HIP_MEMORY_SCOPE_AGENT);
}
// poll until the slot stops being the canary; the returned value is the data
__device__ __forceinline__ float poll_f(const float* p) {
  float v = lda_f(p);
  while (__float_as_uint(v) == CANARY) {
    __builtin_amdgcn_s_sleep(1);
    v = lda_f(p);
  }
  return v;
}

// ---------------------------------------------------------------------------
// Input-dtype detector: even-indexed ushorts of h0 are valid bf16 exponents
// iff inputs are bf16 (fp32 low-mantissa halves look uniform). 256 samples.
__global__ void k_detect(const void* __restrict__ h0raw) {
  __shared__ int cnt;
  int t = threadIdx.x;
  if (t == 0) cnt = 0;
  __syncthreads();
  const ushort_t* u = (const ushort_t*)h0raw;
  if (t < 256) {
    ushort_t v = u[2 * t];          // in-bounds for both dtypes
    int e = (v >> 7) & 0xFF;
    int ok = (e == 0) || (e >= 96 && e <= 134);
    atomicAdd(&cnt, ok);
  }
  __syncthreads();
  if (t == 0) g_dtype = (cnt >= 160) ? 1 : 0;
}

// ---------------------------------------------------------------------------
// Re-arm the canaries in all chain-output buffers (every launch; ~7 MB).
__global__ void k_poison() {
  const float pv = __uint_as_float(CANARY);
  size_t i = (size_t)blockIdx.x * blockDim.x + threadIdx.x;
  size_t stride = (size_t)gridDim.x * blockDim.x;
  for (size_t k = i; k < (size_t)(SFIX + 1) * H; k += stride) g_Hbuf[k] = pv;
  for (size_t k = i; k < (size_t)NFIX * H; k += stride) {
    g_Sh[k] = pv; g_Sc[k] = pv; g_Hos[k] = pv; g_Has[k] = pv;
  }
}

// ---------------------------------------------------------------------------
__global__ void k_b2f(const void* __restrict__ src, int dsel, int n) {
  float* dst = f_conv(dsel);
  int bf = g_dtype;
  int i = blockIdx.x * blockDim.x + threadIdx.x;
  int stride = gridDim.x * blockDim.x;
  if (bf) {
    const ushort_t* s = (const ushort_t*)src;
    for (; i < n; i += stride) dst[i] = b2f(s[i]);
  } else {
    const float* s = (const float*)src;
    for (; i < n; i += stride) dst[i] = s[i];
  }
}

// ---------------------------------------------------------------------------
__global__ void k_makewe(const int* __restrict__ sent, const void* __restrict__ wemb, int S) {
  int i = blockIdx.x;
  int tok = sent[i];
  if (tok < 0) tok = 0;
  float* dst = g_we + (size_t)i * D;
  if (g_dtype) {
    const ushort_t* src = (const ushort_t*)wemb + (size_t)tok * D;
    for (int j = threadIdx.x; j < D; j += blockDim.x) dst[j] = b2f(src[j]);
  } else {
    const float* src = (const float*)wemb + (size_t)tok * D;
    for (int j = threadIdx.x; j < D; j += blockDim.x) dst[j] = src[j];
  }
}

// ---------------------------------------------------------------------------
// Sequential int-only simulation of the transition system.
__global__ void k_traj(const int* __restrict__ actions, int NACT, int S) {
  int tid = threadIdx.x;
  for (int t = tid; t < NACT; t += blockDim.x) {
    g_bsh[t] = -1; g_csh[t] = -1; g_par[t] = -1; g_map_s[t] = 0;
    g_bot[t] = -1; g_cot[t] = -1;
    g_bre[t] = -1; g_cre[t] = -1; g_map_o[t] = 0;
    g_btok[t] = -1; g_cide[t] = -1; g_redact[t] = 0;
  }
  for (int t = tid; t < S; t += blockDim.x) g_bidx_xb[t] = S - 1 - t;
  __syncthreads();
  if (tid != 0) return;

  int pb = S, ps = 0, po = 0, nsh = 0, nred = 0;
  int slot_id[MAXS + 1], slot_tok[MAXS + 1];
  for (int s = 0; s <= MAXS; s++) { slot_id[s] = -2; slot_tok[s] = -1; }

  for (int t = 0; t < NACT; t++) {
    int a = actions[t];
    g_bufp[t] = pb;
    int rs = (ps < MAXS) ? ps : MAXS;
    g_stksrc[t] = (ps > 0) ? slot_id[rs] : -1;  // -1 empty, -2 zeros, j push id
    g_outsrc[t] = po;
    int tb = S - pb; if (tb < 0) tb = 0; if (tb > S - 1) tb = S - 1;
    if (a == 0) {            // SHIFT
      g_par[nsh] = (ps == 0) ? -1 : slot_id[rs];
      g_map_s[nsh] = t;
      g_bsh[t] = tb; g_csh[t] = t;
      int w = (ps + 1 < MAXS) ? ps + 1 : MAXS;
      slot_id[w] = nsh; slot_tok[w] = tb;
      nsh++; ps++; pb--;
    } else if (a == 1) {     // OUT
      g_bot[t] = tb; g_cot[t] = t;
      g_map_o[po] = t;
      po++; pb--;
    } else {                 // REDUCE
      g_btok[nred] = (ps > 0) ? slot_tok[rs] : -1;
      g_cide[nred] = nred; g_redact[nred] = (a < 0) ? 0 : ((a > 2) ? 2 : a);
      g_bre[t] = nred; g_cre[t] = t;
      g_map_o[po] = t;
      po++; nred++;
      ps = (ps > 0) ? ps - 1 : 0;
    }
    if (pb < 0) pb = 0;
  }
  g_counts[0] = nsh; g_counts[1] = po; g_counts[2] = nred;
}

// ---------------------------------------------------------------------------
// cb[c] = bih+bhh (+ Whh@h0 for entity cells, raw-dtype read)
__global__ void k_cbias(const void* __restrict__ Whh5raw) {
  int idx = blockIdx.x * blockDim.x + threadIdx.x;
  if (idx >= 6 * GH) return;
  int c = idx >> 11, m = idx & (GH - 1);
  float v;
  if (c < 5) v = g_bih5[c * GH + m] + g_bhh5[c * GH + m];
  else       v = g_bihA[m] + g_bhhA[m];
  if (c == 3 || c == 4) {
    size_t base = ((size_t)c * GH + m) * H;
    float acc = 0.f;
    if (g_dtype) {
      const ushort_t* w = (const ushort_t*)Whh5raw;
      for (int k = 0; k < H; k++) acc += b2f(w[base + k]) * g_h0[k];
    } else {
      const float* w = (const float*)Whh5raw;
      for (int k = 0; k < H; k++) acc += w[base + k] * g_h0[k];
    }
    v += acc;
  }
  g_cb[idx] = v;
}

// ---------------------------------------------------------------------------
// Gathered GEMM over selector-resolved fp32 scratch:
// C[cidx[n]] = act( A(MxK) @ Brow(n) + bias )
__global__ __launch_bounds__(256) void k_gemm(
    int asel, int aoff, int M, int K,
    int bsel, int bstride,
    int bidx_sel, int cidx_sel, int N,
    int bias_sel, int cb_off, int csel, int act) {
  const float* A = f_amat(asel) + aoff;
  const float* Bsrc = f_src(bsel);
  const float* bias = f_bias(bias_sel) + cb_off;
  const int* bidx = i_arr(bidx_sel);
  const int* cidx = i_arr(cidx_sel);
  float* C = f_dst(csel);

  int mblk = blockIdx.x * 64, nblk = blockIdx.y * 64;
  __shared__ int rowc[64];
  __shared__ float As[16][68];
  __shared__ float Bs[16][68];
  int tid = threadIdx.x;
  if (tid < 64) {
    int n = nblk + tid;
    int cr = -1;
    if (n < N) cr = cidx ? cidx[n] : n;
    if (cr >= NFIX) cr = -1;
    rowc[tid] = cr;
  }
  __syncthreads();
  bool any = false;
  for (int i = 0; i < 64; i++) if (rowc[i] >= 0) { any = true; break; }
  if (!any) return;

  float acc[4][4] = {};
  int tx = tid & 15, ty = tid >> 4;
  int mm = tid >> 2, kq = (tid & 3) * 4;
  int n = nblk + mm;
  const float* bp = nullptr;
  if (n < N) {
    if (bidx) { int bi = bidx[n]; if (bi >= 0 && bi < NFIX) bp = Bsrc + (size_t)bi * bstride; }
    else bp = Bsrc + (size_t)n * bstride;
  }
  const float* ap = A + (size_t)(mblk + mm) * K + kq;

  for (int k0 = 0; k0 < K; k0 += 16) {
    float4 av = *(const float4*)(ap + k0);
    float4 bv = bp ? *(const float4*)(bp + k0 + kq) : make_float4(0.f, 0.f, 0.f, 0.f);
    As[kq + 0][mm] = av.x; As[kq + 1][mm] = av.y; As[kq + 2][mm] = av.z; As[kq + 3][mm] = av.w;
    Bs[kq + 0][mm] = bv.x; Bs[kq + 1][mm] = bv.y; Bs[kq + 2][mm] = bv.z; Bs[kq + 3][mm] = bv.w;
    __syncthreads();
#pragma unroll
    for (int kk = 0; kk < 16; kk++) {
      float a0 = As[kk][tx * 4 + 0], a1 = As[kk][tx * 4 + 1];
      float a2 = As[kk][tx * 4 + 2], a3 = As[kk][tx * 4 + 3];
      float b0 = Bs[kk][ty * 4 + 0], b1 = Bs[kk][ty * 4 + 1];
      float b2 = Bs[kk][ty * 4 + 2], b3 = Bs[kk][ty * 4 + 3];
      acc[0][0] = fmaf(b0, a0, acc[0][0]); acc[0][1] = fmaf(b0, a1, acc[0][1]);
      acc[0][2] = fmaf(b0, a2, acc[0][2]); acc[0][3] = fmaf(b0, a3, acc[0][3]);
      acc[1][0] = fmaf(b1, a0, acc[1][0]); acc[1][1] = fmaf(b1, a1, acc[1][1]);
      acc[1][2] = fmaf(b1, a2, acc[1][2]); acc[1][3] = fmaf(b1, a3, acc[1][3]);
      acc[2][0] = fmaf(b2, a0, acc[2][0]); acc[2][1] = fmaf(b2, a1, acc[2][1]);
      acc[2][2] = fmaf(b2, a2, acc[2][2]); acc[2][3] = fmaf(b2, a3, acc[2][3]);
      acc[3][0] = fmaf(b3, a0, acc[3][0]); acc[3][1] = fmaf(b3, a1, acc[3][1]);
      acc[3][2] = fmaf(b3, a2, acc[3][2]); acc[3][3] = fmaf(b3, a3, acc[3][3]);
    }
    __syncthreads();
  }
#pragma unroll
  for (int i = 0; i < 4; i++) {
    int crow = rowc[ty * 4 + i];
    if (crow < 0) continue;
    int mj = mblk + tx * 4;
    float4 v;
    v.x = acc[i][0] + bias[mj + 0];
    v.y = acc[i][1] + bias[mj + 1];
    v.z = acc[i][2] + bias[mj + 2];
    v.w = acc[i][3] + bias[mj + 3];
    if (act) { v.x = tanhf(v.x); v.y = tanhf(v.y); v.z = tanhf(v.z); v.w = tanhf(v.w); }
    *(float4*)(C + (size_t)crow * M + mj) = v;
  }
}

// ---------------------------------------------------------------------------
// Entity epilogues (two passes over g_E).
__global__ void k_entityA() {
  int r = blockIdx.x;
  if (g_cide[r] < 0) return;
  int j = threadIdx.x;  // 512
  const float* z = g_E + (size_t)r * GH;
  float zi = z[j], zf = z[j + 512], zg = z[j + 1024], zo = z[j + 1536];
  float i_ = 1.f / (1.f + expf(-zi));
  float f_ = 1.f / (1.f + expf(-zf));
  float o_ = 1.f / (1.f + expf(-zo));
  float c2 = f_ * g_c0[j] + i_ * tanhf(zg);
  g_Bent[(size_t)r * 1152 + j] = o_ * tanhf(c2);
  if (j < DA) g_Bent[(size_t)r * 1152 + 1024 + j] = g_remb[g_redact[r] * DA + j];
}
__global__ void k_entityB() {
  int r = blockIdx.x;
  if (g_cide[r] < 0) return;
  int j = threadIdx.x;  // 512
  const float* z = g_E + (size_t)r * GH;
  float zi = z[j], zf = z[j + 512], zg = z[j + 1024], zo = z[j + 1536];
  float i_ = 1.f / (1.f + expf(-zi));
  float f_ = 1.f / (1.f + expf(-zf));
  float o_ = 1.f / (1.f + expf(-zo));
  float c2 = f_ * g_c0[j] + i_ * tanhf(zg);
  g_Bent[(size_t)r * 1152 + 512 + j] = o_ * tanhf(c2);
}

// ---------------------------------------------------------------------------
// MULTI-WORKGROUP chains with DATA-AS-SIGNAL (canary) sync.
//
// Structure identical to the validated R3 kernel (16 WGs x 512 thr per
// chain, register-resident weights, LDS h-broadcast matvec). Protocol
// change: chain-output buffers are pre-poisoned with a NaN canary
// (k_poison); each step's h/c go to fresh locations, so a consumer simply
// polls its own element until it stops being the canary — the successful
// poll IS the data read. This removes the per-step tag publish, tag poll,
// vmcnt drain and one barrier: one producer store + one consumer poll-hit
// of MALL latency per step instead of ~4 round trips.
//
// Barrier analysis (2 per step): B1 (after poll/LDS write) orders hsh
// ready AND prev-iter psh gate-reads before this iter's psh writes;
// B2 orders psh ready before gates. Own-WG consumers of the gate lanes'
// stores are held at their poll -> natural back-pressure, no WAR races.
// Deadlock-free: polls only wait on data from strictly earlier steps.
__global__ __launch_bounds__(512, 1) void k_chain_mw(
    const int* __restrict__ acts,
    const void* __restrict__ Whh5raw, const void* __restrict__ WhhAraw,
    int S, int NACT) {
  const int bid = blockIdx.x;
  const int chain = bid & 3;                   // 0..3
  const int wslot = bid >> 2;                  // 0..15
  const int j0 = wslot * 32;
  const int t = threadIdx.x;                   // 0..511
  const int chunk = t >> 6;                    // 0..7 == wave id
  const int rl = t & 63;
  const int m0 = (rl >> 5) * 512 + j0 + (rl & 31);   // gates 0-1
  const int m1 = m0 + 1024;                          // gates 2-3
  const int kb = chunk * 64;

  float* outH; int nsteps;
  if (chain == 0)      { outH = g_Hbuf + H; nsteps = S; }
  else if (chain == 1) { outH = g_Sh;       nsteps = g_counts[0]; }
  else if (chain == 2) { outH = g_Hos;      nsteps = g_counts[1]; }
  else                 { outH = g_Has;      nsteps = NACT; }
  if (nsteps > NFIX) nsteps = NFIX;

  // ---- one-time: weight slices -> registers (raw dtype) ----
  float4 wv0[16], wv1[16];
  if (g_dtype) {
    const ushort_t* base = (chain < 3) ? (const ushort_t*)Whh5raw + (size_t)chain * GH * H
                                       : (const ushort_t*)WhhAraw;
    const ushort_t* p0 = base + (size_t)m0 * H + kb;
    const ushort_t* p1 = base + (size_t)m1 * H + kb;
#pragma unroll
    for (int i = 0; i < 16; i++) {
      ushort4 u0 = *(const ushort4*)(p0 + 4 * i);
      ushort4 u1 = *(const ushort4*)(p1 + 4 * i);
      wv0[i].x = b2f(u0.x); wv0[i].y = b2f(u0.y); wv0[i].z = b2f(u0.z); wv0[i].w = b2f(u0.w);
      wv1[i].x = b2f(u1.x); wv1[i].y = b2f(u1.y); wv1[i].z = b2f(u1.z); wv1[i].w = b2f(u1.w);
    }
  } else {
    const float* base = (chain < 3) ? (const float*)Whh5raw + (size_t)chain * GH * H
                                    : (const float*)WhhAraw;
    const float* p0 = base + (size_t)m0 * H + kb;
    const float* p1 = base + (size_t)m1 * H + kb;
#pragma unroll
    for (int i = 0; i < 16; i++) {
      wv0[i] = *(const float4*)(p0 + 4 * i);
      wv1[i] = *(const float4*)(p1 + 4 * i);
    }
  }

  __shared__ float4 hsh4[128];     // prev hidden state (512 floats)
  __shared__ float  psh[8][128];   // chunk partials
  __shared__ float  csh[32];       // running cell state (chains != 1)
  if (chain != 1 && t < 32) csh[t] = g_c0[j0 + t];

  for (int s = 0; s < nsteps; s++) {
    // x input row (precomputed, read-only, cached loads) — before the poll
    const float* xrow;
    if (chain == 0)      xrow = g_XB + (size_t)s * GH;
    else if (chain == 1) { int mm = g_map_s[s]; if (mm < 0) mm = 0; if (mm >= NFIX) mm = NFIX - 1;
                           xrow = g_Xso + (size_t)mm * GH; }
    else if (chain == 2) { int mm = g_map_o[s]; if (mm < 0) mm = 0; if (mm >= NFIX) mm = NFIX - 1;
                           xrow = g_Xso + (size_t)mm * GH; }
    else                 { int a = acts[s]; if (a < 0) a = 0; if (a > 2) a = 2;
                           xrow = g_Pa + (size_t)a * GH; }
    float xv0 = 0.f, xv1 = 0.f;
    if (chunk == 0) { xv0 = xrow[m0]; xv1 = xrow[m1]; }

    // previous hidden state source
    int pval = -1;
    const float* hp;
    if (chain == 1) {
      int p = g_par[s]; if (p >= NFIX) p = NFIX - 1;
      pval = p;
      hp = (p == -1) ? g_h0 : ((p < -1) ? nullptr : g_Sh + (size_t)p * H);
    } else {
      hp = (s == 0) ? g_h0 : outH + (size_t)(s - 1) * H;
    }
    const bool h_local = (chain != 1) ? (s == 0) : (pval == -1);  // g_h0: plain read

    // ---- canary-poll prev h: the data itself is the sync signal ----
    {
      float v;
      if (h_local)          v = hp[t];
      else if (hp == nullptr) v = 0.f;
      else                  v = poll_f(hp + t);
      ((float*)hsh4)[t] = v;
    }
    __syncthreads();   // B1: hsh ready; prev-iter psh reads ordered before new writes

    // matvec: one wave-uniform LDS broadcast read feeds 8 FMAs
    float4 a0 = make_float4(0.f, 0.f, 0.f, 0.f);
    float4 a1 = make_float4(0.f, 0.f, 0.f, 0.f);
#pragma unroll
    for (int i = 0; i < 16; i++) {
      float4 hv = hsh4[(chunk << 4) + i];
      a0.x = fmaf(wv0[i].x, hv.x, a0.x);
      a0.y = fmaf(wv0[i].y, hv.y, a0.y);
      a0.z = fmaf(wv0[i].z, hv.z, a0.z);
      a0.w = fmaf(wv0[i].w, hv.w, a0.w);
      a1.x = fmaf(wv1[i].x, hv.x, a1.x);
      a1.y = fmaf(wv1[i].y, hv.y, a1.y);
      a1.z = fmaf(wv1[i].z, hv.z, a1.z);
      a1.w = fmaf(wv1[i].w, hv.w, a1.w);
    }
    float pp0 = (a0.x + a0.y) + (a0.z + a0.w);
    float pp1 = (a1.x + a1.y) + (a1.z + a1.w);
    if (chunk == 0) { pp0 += xv0; pp1 += xv1; }
    psh[chunk][rl] = pp0;
    psh[chunk][rl + 64] = pp1;
    __syncthreads();   // B2: partials ready

    // gates + state update + slice store (lanes 0..31 of wave 0)
    if (t < 32) {
      float zi = 0.f, zf = 0.f, zg = 0.f, zo = 0.f;
#pragma unroll
      for (int c = 0; c < 8; c++) {
        zi += psh[c][t];
        zf += psh[c][32 + t];
        zg += psh[c][64 + t];
        zo += psh[c][96 + t];
      }
      float i_ = 1.f / (1.f + expf(-zi));
      float f_ = 1.f / (1.f + expf(-zf));
      float o_ = 1.f / (1.f + expf(-zo));
      int j = j0 + t;
      float cprev;
      if (chain == 1) {
        if (pval == -1)      cprev = g_c0[j];
        else if (pval < -1)  cprev = 0.f;
        else                 cprev = poll_f(&g_Sc[(size_t)pval * H + j]);
      } else {
        cprev = csh[t];
      }
      float c2 = f_ * cprev + i_ * tanhf(zg);
      float hn = o_ * tanhf(c2);
      if (chain == 1) sta_f(&g_Sc[(size_t)s * H + j], c2);
      else            csh[t] = c2;
      sta_f(&outH[(size_t)s * H + j], hn);
      // no drain, no tag: the store replacing the canary IS the publish
    }
  }
}

// ---------------------------------------------------------------------------
__global__ void k_feat() {
  int t = blockIdx.x;
  int j = threadIdx.x;  // 512
  float* f = g_feat + (size_t)t * GH;
  int s = g_stksrc[t]; if (s >= NFIX) s = NFIX - 1;
  f[j] = (s == -1) ? g_empty[j] : ((s < 0) ? 0.f : g_Sh[(size_t)s * H + j]);
  int p = g_bufp[t]; if (p > SFIX) p = SFIX;
  f[H + j] = (p > 0) ? g_Hbuf[(size_t)p * H + j] : g_empty[j];
  int k = g_outsrc[t]; if (k > NFIX) k = NFIX;
  f[2 * H + j] = (k > 0) ? g_Hos[(size_t)(k - 1) * H + j] : g_empty[j];
  f[3 * H + j] = (t > 0) ? g_Has[(size_t)(t - 1) * H + j] : g_empty[j];
}

// ---------------------------------------------------------------------------
__global__ void k_final(const int* __restrict__ actions, void* __restrict__ out) {
  int t = blockIdx.x;
  int lane = threadIdx.x;  // 64
  const float* tv = g_t1 + (size_t)t * H;
  float a0 = 0.f, a1 = 0.f, a2 = 0.f;
  for (int j = lane; j < H; j += 64) {
    float v = tv[j];
    a0 += g_W2[j] * v; a1 += g_W2[H + j] * v; a2 += g_W2[2 * H + j] * v;
  }
  for (int off = 32; off; off >>= 1) {
    a0 += __shfl_down(a0, off);
    a1 += __shfl_down(a1, off);
    a2 += __shfl_down(a2, off);
  }
  if (lane == 0) {
    a0 += g_b2[0]; a1 += g_b2[1]; a2 += g_b2[2];
    float m = fmaxf(a0, fmaxf(a1, a2));
    float lse = m + logf(expf(a0 - m) + expf(a1 - m) + expf(a2 - m));
    int a = actions[t];
    float la = (a <= 0) ? a0 : ((a == 1) ? a1 : a2);
    float v = lse - la;
    if (g_dtype) {
      unsigned int b = __float_as_uint(v);
      b += 0x7FFFu + ((b >> 16) & 1u);     // RNE to bf16
      ((ushort_t*)out)[t] = (ushort_t)(b >> 16);
    } else {
      ((float*)out)[t] = v;
    }
  }
}

// ---------------------------------------------------------------------------
extern "C" void kernel_launch(void* const* d_in, const int* in_sizes, int n_in,
                              void* d_out, int out_size, void* d_ws, size_t ws_size,
                              hipStream_t stream) {
  const int* sent   = (const int*)d_in[0];
  const int* actions= (const int*)d_in[1];
  const void* wemb  = d_in[2];
  const void* aemb  = d_in[3];
  const void* remb  = d_in[4];
  const void* empty = d_in[5];
  const void* h0    = d_in[6];
  const void* c0    = d_in[7];
  const void* Wih5  = d_in[8];
  const void* Whh5  = d_in[9];
  const void* bih5  = d_in[10];
  const void* bhh5  = d_in[11];
  const void* Wih_a = d_in[12];
  const void* Whh_a = d_in[13];
  const void* bih_a = d_in[14];
  const void* bhh_a = d_in[15];
  const void* W1    = d_in[16];
  const void* b1    = d_in[17];
  const void* W2    = d_in[18];
  const void* b2    = d_in[19];
  const void* We    = d_in[20];
  const void* be    = d_in[21];
  int S = in_sizes[0];    // 512
  int NACT = in_sizes[1]; // 768
  if (S > SFIX) S = SFIX;
  if (NACT > NFIX) NACT = NFIX;
  (void)n_in; (void)out_size; (void)d_ws; (void)ws_size;

  k_detect<<<1, 256, 0, stream>>>(h0);
  k_poison<<<1024, 256, 0, stream>>>();   // re-arm canaries every launch

  auto conv = [&](const void* src, int dsel, int n) {
    int blocks = (n + 255) / 256; if (blocks > 1024) blocks = 1024;
    k_b2f<<<blocks, 256, 0, stream>>>(src, dsel, n);
  };
  conv(Wih5, 0, 5 * GH * D);
  conv(Wih_a, 1, GH * DA);
  conv(W1, 2, H * GH);
  conv(We, 3, H * (2 * H + DA));
  conv(W2, 4, 3 * H);
  conv(aemb, 5, 3 * DA);
  conv(remb, 6, 3 * DA);
  conv(empty, 7, H);
  conv(h0, 8, H);
  conv(c0, 9, H);
  conv(b1, 10, H);
  conv(be, 11, D);
  conv(b2, 12, 3);
  conv(bih5, 13, 5 * GH);
  conv(bhh5, 14, 5 * GH);
  conv(bih_a, 15, GH);
  conv(bhh_a, 16, GH);

  k_makewe<<<S, 256, 0, stream>>>(sent, wemb, S);
  k_traj<<<1, 64, 0, stream>>>(actions, NACT, S);
  k_cbias<<<(6 * GH + 255) / 256, 256, 0, stream>>>(Whh5);

  dim3 gPa(GH / 64, 1);
  dim3 gXB(GH / 64, (S + 63) / 64);
  dim3 gN(GH / 64, (NACT + 63) / 64);
  dim3 gH(H / 64, (NACT + 63) / 64);
  // Pa[a] = WihA @ aemb[a] + cb5  (3 distinct actions)
  k_gemm<<<gPa, 256, 0, stream>>>(1, 0, GH, DA, 4, DA, -1, -1, 3, 0, 5 * GH, 0, 0);
  // XB = Wih0 @ we[reversed] + cb0
  k_gemm<<<gXB, 256, 0, stream>>>(0, 0, GH, D, 0, D, 0, -1, S, 0, 0, 1, 0);
  // Xso[t] SHIFT: Wih1 @ we[tok] + cb1
  k_gemm<<<gN, 256, 0, stream>>>(0, 1 * GH * D, GH, D, 0, D, 1, 2, NACT, 0, GH, 2, 0);
  // Xso[t] OUT: Wih2 @ we[tok] + cb2
  k_gemm<<<gN, 256, 0, stream>>>(0, 2 * GH * D, GH, D, 0, D, 3, 4, NACT, 0, 2 * GH, 2, 0);
  // E = Wih3 @ we[reduce tok] + cb3 ; entity-fwd -> Bent[:, :512]
  k_gemm<<<gN, 256, 0, stream>>>(0, 3 * GH * D, GH, D, 0, D, 7, 8, NACT, 0, 3 * GH, 3, 0);
  k_entityA<<<NACT, 512, 0, stream>>>();
  // E = Wih4 @ we[reduce tok] + cb4 ; entity-bwd -> Bent[:, 512:1024]
  k_gemm<<<gN, 256, 0, stream>>>(0, 4 * GH * D, GH, D, 0, D, 7, 8, NACT, 0, 4 * GH, 3, 0);
  k_entityB<<<NACT, 512, 0, stream>>>();
  // ent = tanh(We @ Bent + be)
  k_gemm<<<gH, 256, 0, stream>>>(2, 0, H, 2 * H + DA, 2, 1152, -1, 8, NACT, 1, 0, 4, 1);
  // Xso[t] REDUCE: Wih2 @ ent[r] + cb2
  k_gemm<<<gN, 256, 0, stream>>>(0, 2 * GH * D, GH, D, 1, H, 5, 6, NACT, 0, 2 * GH, 2, 0);
  // Four LSTM recurrences: 16 WGs each, canary data-as-signal sync.
  k_chain_mw<<<64, 512, 0, stream>>>(actions, Whh5, Whh_a, S, NACT);
  k_feat<<<NACT, 512, 0, stream>>>();
  // t1 = tanh(W1 @ feat + b1)
  k_gemm<<<gH, 256, 0, stream>>>(3, 0, H, GH, 3, GH, -1, -1, NACT, 2, 0, 5, 1);
  k_final<<<NACT, 64, 0, stream>>>(actions, d_out);
}

// Round 6
// 1954.054 us; speedup vs baseline: 2.6147x; 1.1428x over previous
//
#include <hip/hip_runtime.h>
#include <math.h>

#define H 512
#define D 512
#define DA 128
#define MAXS 8
#define GH 2048   // 4*H
#define SFIX 512
#define NFIX 768
#define WPC 16    // workgroups per chain
#define CANARY 0x7FC00BADu   // quiet-NaN poison: unreachable by LSTM outputs

typedef unsigned short ushort_t;

__device__ __forceinline__ float b2f(ushort_t v) {
  return __uint_as_float(((unsigned int)v) << 16);
}
// fast-math gates: v_exp_f32 based; |err| ~1e-6 << bf16 output ULP.
__device__ __forceinline__ float sigm_f(float x) {
  return 1.f / (1.f + __expf(-x));
}
__device__ __forceinline__ float tanh_f(float x) {
  return 1.f - 2.f / (1.f + __expf(2.f * x));   // saturates correctly at +-inf
}

// ---------------------------------------------------------------------------
// All scratch in module __device__ globals. d_ws untouched.
__device__ int   g_dtype;          // 1 = inputs are bf16, 0 = fp32
// fp32 copies of inputs:
__device__ float g_Wih5[5 * GH * D];
__device__ float g_WihA[GH * DA];
__device__ float g_W1[H * GH];
__device__ float g_We[H * (2 * H + DA)];
__device__ float g_W2[3 * H];
__device__ float g_aemb[3 * DA];
__device__ float g_remb[3 * DA];
__device__ float g_empty[H];
__device__ float g_h0[H];
__device__ float g_c0[H];
__device__ float g_b1[H];
__device__ float g_be[D];
__device__ float g_b2[4];
__device__ float g_bih5[5 * GH];
__device__ float g_bhh5[5 * GH];
__device__ float g_bihA[GH];
__device__ float g_bhhA[GH];
// trajectory index lists:
__device__ int g_bidx_xb[SFIX];
__device__ int g_bsh[NFIX], g_csh[NFIX], g_par[NFIX], g_map_s[NFIX];
__device__ int g_bot[NFIX], g_cot[NFIX];
__device__ int g_bre[NFIX], g_cre[NFIX], g_map_o[NFIX];
__device__ int g_btok[NFIX], g_cide[NFIX], g_redact[NFIX];
__device__ int g_bufp[NFIX], g_stksrc[NFIX], g_outsrc[NFIX];
__device__ int g_counts[16];
// pipeline buffers:
__device__ float g_we[SFIX * D];
__device__ float g_cb[6 * GH];
__device__ float g_Pa[3 * GH];
__device__ float g_XB[SFIX * GH];
__device__ float g_Xso[NFIX * GH];
__device__ float g_E[NFIX * GH];
__device__ float g_E2[NFIX * GH];
__device__ float g_Bent[NFIX * 1152];
__device__ float g_ent[NFIX * H];
__device__ float g_Hbuf[(SFIX + 1) * H];
__device__ float g_Sh[NFIX * H], g_Sc[NFIX * H];
__device__ float g_Hos[NFIX * H], g_Has[NFIX * H];
__device__ float g_feat[NFIX * GH];
__device__ float g_t1[NFIX * H];

// device-side selectors (host cannot take addresses of __device__ globals)
__device__ __forceinline__ float* f_conv(int s) {
  switch (s) {
    case 0: return g_Wih5;  case 1: return g_WihA;  case 2: return g_W1;
    case 3: return g_We;    case 4: return g_W2;    case 5: return g_aemb;
    case 6: return g_remb;  case 7: return g_empty; case 8: return g_h0;
    case 9: return g_c0;    case 10: return g_b1;   case 11: return g_be;
    case 12: return g_b2;   case 13: return g_bih5; case 14: return g_bhh5;
    case 15: return g_bihA; case 16: return g_bhhA;
    default: return nullptr;
  }
}
__device__ __forceinline__ const float* f_amat(int s) {
  switch (s) {
    case 0: return g_Wih5; case 1: return g_WihA;
    case 2: return g_We;   case 3: return g_W1;
    default: return nullptr;
  }
}
__device__ __forceinline__ const float* f_src(int s) {
  switch (s) {
    case 0: return g_we;   case 1: return g_ent; case 2: return g_Bent;
    case 3: return g_feat; case 4: return g_aemb;
    default: return nullptr;
  }
}
__device__ __forceinline__ float* f_dst(int s) {
  switch (s) {
    case 0: return g_Pa;  case 1: return g_XB;  case 2: return g_Xso;
    case 3: return g_E;   case 4: return g_ent; case 5: return g_t1;
    case 6: return g_E2;
    default: return nullptr;
  }
}
__device__ __forceinline__ const float* f_bias(int s) {
  switch (s) {
    case 0: return g_cb; case 1: return g_be; case 2: return g_b1;
    default: return nullptr;
  }
}
__device__ __forceinline__ const int* i_arr(int s) {
  switch (s) {
    case 0: return g_bidx_xb;
    case 1: return g_bsh;  case 2: return g_csh;
    case 3: return g_bot;  case 4: return g_cot;
    case 5: return g_bre;  case 6: return g_cre;
    case 7: return g_btok; case 8: return g_cide;
    default: return nullptr;
  }
}

// ---------------------------------------------------------------------------
// MALL-coherent (agent-scope) scalar accesses — compiler-lowered, no asm.
__device__ __forceinline__ float lda_f(const float* p) {
  return __hip_atomic_load(p, __ATOMIC_RELAXED, __HIP_MEMORY_SCOPE_AGENT);
}
__device__ __forceinline__ void sta_f(float* p, float v) {
  __hip_atomic_store(p, v, __ATOMIC_RELAXED, __HIP_MEMORY_SCOPE_AGENT);
}
// poll until the slot stops being the canary; the returned value is the data
__device__ __forceinline__ float poll_f(const float* p) {
  float v = lda_f(p);
  while (__float_as_uint(v) == CANARY) {
    __builtin_amdgcn_s_sleep(1);
    v = lda_f(p);
  }
  return v;
}

// ---------------------------------------------------------------------------
// Input-dtype detector: even-indexed ushorts of h0 are valid bf16 exponents
// iff inputs are bf16 (fp32 low-mantissa halves look uniform). 256 samples.
__global__ void k_detect(const void* __restrict__ h0raw) {
  __shared__ int cnt;
  int t = threadIdx.x;
  if (t == 0) cnt = 0;
  __syncthreads();
  const ushort_t* u = (const ushort_t*)h0raw;
  if (t < 256) {
    ushort_t v = u[2 * t];          // in-bounds for both dtypes
    int e = (v >> 7) & 0xFF;
    int ok = (e == 0) || (e >= 96 && e <= 134);
    atomicAdd(&cnt, ok);
  }
  __syncthreads();
  if (t == 0) g_dtype = (cnt >= 160) ? 1 : 0;
}

// ---------------------------------------------------------------------------
// Re-arm the canaries in all chain-output buffers (every launch; ~7 MB).
__global__ void k_poison() {
  const float pv = __uint_as_float(CANARY);
  size_t i = (size_t)blockIdx.x * blockDim.x + threadIdx.x;
  size_t stride = (size_t)gridDim.x * blockDim.x;
  for (size_t k = i; k < (size_t)(SFIX + 1) * H; k += stride) g_Hbuf[k] = pv;
  for (size_t k = i; k < (size_t)NFIX * H; k += stride) {
    g_Sh[k] = pv; g_Sc[k] = pv; g_Hos[k] = pv; g_Has[k] = pv;
  }
}

// ---------------------------------------------------------------------------
__global__ void k_b2f(const void* __restrict__ src, int dsel, int n) {
  float* dst = f_conv(dsel);
  int bf = g_dtype;
  int i = blockIdx.x * blockDim.x + threadIdx.x;
  int stride = gridDim.x * blockDim.x;
  if (bf) {
    const ushort_t* s = (const ushort_t*)src;
    for (; i < n; i += stride) dst[i] = b2f(s[i]);
  } else {
    const float* s = (const float*)src;
    for (; i < n; i += stride) dst[i] = s[i];
  }
}

// ---------------------------------------------------------------------------
__global__ void k_makewe(const int* __restrict__ sent, const void* __restrict__ wemb, int S) {
  int i = blockIdx.x;
  int tok = sent[i];
  if (tok < 0) tok = 0;
  float* dst = g_we + (size_t)i * D;
  if (g_dtype) {
    const ushort_t* src = (const ushort_t*)wemb + (size_t)tok * D;
    for (int j = threadIdx.x; j < D; j += blockDim.x) dst[j] = b2f(src[j]);
  } else {
    const float* src = (const float*)wemb + (size_t)tok * D;
    for (int j = threadIdx.x; j < D; j += blockDim.x) dst[j] = src[j];
  }
}

// ---------------------------------------------------------------------------
// Sequential int-only simulation of the transition system.
__global__ void k_traj(const int* __restrict__ actions, int NACT, int S) {
  int tid = threadIdx.x;
  for (int t = tid; t < NACT; t += blockDim.x) {
    g_bsh[t] = -1; g_csh[t] = -1; g_par[t] = -1; g_map_s[t] = 0;
    g_bot[t] = -1; g_cot[t] = -1;
    g_bre[t] = -1; g_cre[t] = -1; g_map_o[t] = 0;
    g_btok[t] = -1; g_cide[t] = -1; g_redact[t] = 0;
  }
  for (int t = tid; t < S; t += blockDim.x) g_bidx_xb[t] = S - 1 - t;
  __syncthreads();
  if (tid != 0) return;

  int pb = S, ps = 0, po = 0, nsh = 0, nred = 0;
  int slot_id[MAXS + 1], slot_tok[MAXS + 1];
  for (int s = 0; s <= MAXS; s++) { slot_id[s] = -2; slot_tok[s] = -1; }

  for (int t = 0; t < NACT; t++) {
    int a = actions[t];
    g_bufp[t] = pb;
    int rs = (ps < MAXS) ? ps : MAXS;
    g_stksrc[t] = (ps > 0) ? slot_id[rs] : -1;  // -1 empty, -2 zeros, j push id
    g_outsrc[t] = po;
    int tb = S - pb; if (tb < 0) tb = 0; if (tb > S - 1) tb = S - 1;
    if (a == 0) {            // SHIFT
      g_par[nsh] = (ps == 0) ? -1 : slot_id[rs];
      g_map_s[nsh] = t;
      g_bsh[t] = tb; g_csh[t] = t;
      int w = (ps + 1 < MAXS) ? ps + 1 : MAXS;
      slot_id[w] = nsh; slot_tok[w] = tb;
      nsh++; ps++; pb--;
    } else if (a == 1) {     // OUT
      g_bot[t] = tb; g_cot[t] = t;
      g_map_o[po] = t;
      po++; pb--;
    } else {                 // REDUCE
      g_btok[nred] = (ps > 0) ? slot_tok[rs] : -1;
      g_cide[nred] = nred; g_redact[nred] = (a < 0) ? 0 : ((a > 2) ? 2 : a);
      g_bre[t] = nred; g_cre[t] = t;
      g_map_o[po] = t;
      po++; nred++;
      ps = (ps > 0) ? ps - 1 : 0;
    }
    if (pb < 0) pb = 0;
  }
  g_counts[0] = nsh; g_counts[1] = po; g_counts[2] = nred;
}

// ---------------------------------------------------------------------------
// cb[c] = bih+bhh (+ Whh@h0 for entity cells, raw-dtype read)
__global__ void k_cbias(const void* __restrict__ Whh5raw) {
  int idx = blockIdx.x * blockDim.x + threadIdx.x;
  if (idx >= 6 * GH) return;
  int c = idx >> 11, m = idx & (GH - 1);
  float v;
  if (c < 5) v = g_bih5[c * GH + m] + g_bhh5[c * GH + m];
  else       v = g_bihA[m] + g_bhhA[m];
  if (c == 3 || c == 4) {
    size_t base = ((size_t)c * GH + m) * H;
    float acc = 0.f;
    if (g_dtype) {
      const ushort_t* w = (const ushort_t*)Whh5raw;
      for (int k = 0; k < H; k++) acc += b2f(w[base + k]) * g_h0[k];
    } else {
      const float* w = (const float*)Whh5raw;
      for (int k = 0; k < H; k++) acc += w[base + k] * g_h0[k];
    }
    v += acc;
  }
  g_cb[idx] = v;
}

// ---------------------------------------------------------------------------
// Gathered GEMM body over selector-resolved fp32 scratch:
// C[cidx[n]] = act( A(MxK) @ Brow(n) + bias )
__device__ void gemm_body(
    int asel, int aoff, int M, int K,
    int bsel, int bstride,
    int bidx_sel, int cidx_sel, int N,
    int bias_sel, int cb_off, int csel, int act,
    int bx, int by) {
  const float* A = f_amat(asel) + aoff;
  const float* Bsrc = f_src(bsel);
  const float* bias = f_bias(bias_sel) + cb_off;
  const int* bidx = i_arr(bidx_sel);
  const int* cidx = i_arr(cidx_sel);
  float* C = f_dst(csel);

  int mblk = bx * 64, nblk = by * 64;
  __shared__ int rowc[64];
  __shared__ float As[16][68];
  __shared__ float Bs[16][68];
  int tid = threadIdx.x;
  if (tid < 64) {
    int n = nblk + tid;
    int cr = -1;
    if (n < N) cr = cidx ? cidx[n] : n;
    if (cr >= NFIX) cr = -1;
    rowc[tid] = cr;
  }
  __syncthreads();
  bool any = false;
  for (int i = 0; i < 64; i++) if (rowc[i] >= 0) { any = true; break; }
  if (!any) return;

  float acc[4][4] = {};
  int tx = tid & 15, ty = tid >> 4;
  int mm = tid >> 2, kq = (tid & 3) * 4;
  int n = nblk + mm;
  const float* bp = nullptr;
  if (n < N) {
    if (bidx) { int bi = bidx[n]; if (bi >= 0 && bi < NFIX) bp = Bsrc + (size_t)bi * bstride; }
    else bp = Bsrc + (size_t)n * bstride;
  }
  const float* ap = A + (size_t)(mblk + mm) * K + kq;

  for (int k0 = 0; k0 < K; k0 += 16) {
    float4 av = *(const float4*)(ap + k0);
    float4 bv = bp ? *(const float4*)(bp + k0 + kq) : make_float4(0.f, 0.f, 0.f, 0.f);
    As[kq + 0][mm] = av.x; As[kq + 1][mm] = av.y; As[kq + 2][mm] = av.z; As[kq + 3][mm] = av.w;
    Bs[kq + 0][mm] = bv.x; Bs[kq + 1][mm] = bv.y; Bs[kq + 2][mm] = bv.z; Bs[kq + 3][mm] = bv.w;
    __syncthreads();
#pragma unroll
    for (int kk = 0; kk < 16; kk++) {
      float a0 = As[kk][tx * 4 + 0], a1 = As[kk][tx * 4 + 1];
      float a2 = As[kk][tx * 4 + 2], a3 = As[kk][tx * 4 + 3];
      float b0 = Bs[kk][ty * 4 + 0], b1 = Bs[kk][ty * 4 + 1];
      float b2 = Bs[kk][ty * 4 + 2], b3 = Bs[kk][ty * 4 + 3];
      acc[0][0] = fmaf(b0, a0, acc[0][0]); acc[0][1] = fmaf(b0, a1, acc[0][1]);
      acc[0][2] = fmaf(b0, a2, acc[0][2]); acc[0][3] = fmaf(b0, a3, acc[0][3]);
      acc[1][0] = fmaf(b1, a0, acc[1][0]); acc[1][1] = fmaf(b1, a1, acc[1][1]);
      acc[1][2] = fmaf(b1, a2, acc[1][2]); acc[1][3] = fmaf(b1, a3, acc[1][3]);
      acc[2][0] = fmaf(b2, a0, acc[2][0]); acc[2][1] = fmaf(b2, a1, acc[2][1]);
      acc[2][2] = fmaf(b2, a2, acc[2][2]); acc[2][3] = fmaf(b2, a3, acc[2][3]);
      acc[3][0] = fmaf(b3, a0, acc[3][0]); acc[3][1] = fmaf(b3, a1, acc[3][1]);
      acc[3][2] = fmaf(b3, a2, acc[3][2]); acc[3][3] = fmaf(b3, a3, acc[3][3]);
    }
    __syncthreads();
  }
#pragma unroll
  for (int i = 0; i < 4; i++) {
    int crow = rowc[ty * 4 + i];
    if (crow < 0) continue;
    int mj = mblk + tx * 4;
    float4 v;
    v.x = acc[i][0] + bias[mj + 0];
    v.y = acc[i][1] + bias[mj + 1];
    v.z = acc[i][2] + bias[mj + 2];
    v.w = acc[i][3] + bias[mj + 3];
    if (act) { v.x = tanh_f(v.x); v.y = tanh_f(v.y); v.z = tanh_f(v.z); v.w = tanh_f(v.w); }
    *(float4*)(C + (size_t)crow * M + mj) = v;
  }
}

__global__ __launch_bounds__(256) void k_gemm(
    int asel, int aoff, int M, int K,
    int bsel, int bstride,
    int bidx_sel, int cidx_sel, int N,
    int bias_sel, int cb_off, int csel, int act) {
  gemm_body(asel, aoff, M, K, bsel, bstride, bidx_sel, cidx_sel, N,
            bias_sel, cb_off, csel, act, blockIdx.x, blockIdx.y);
}

// Mega-dispatch of the 6 independent stage-1 GEMMs (Pa, XB, SHIFT, OUT,
// E-fwd, E-bwd->g_E2). o1..o5 are job start-block offsets; all jobs gx=32.
__global__ __launch_bounds__(256) void k_gemm_mega(
    int o1, int o2, int o3, int o4, int o5, int S, int NACT) {
  int bid = blockIdx.x;
  int job, base;
  if (bid < o1)      { job = 0; base = 0;  }
  else if (bid < o2) { job = 1; base = o1; }
  else if (bid < o3) { job = 2; base = o2; }
  else if (bid < o4) { job = 3; base = o3; }
  else if (bid < o5) { job = 4; base = o4; }
  else               { job = 5; base = o5; }
  int rel = bid - base, bx = rel & 31, by = rel >> 5;
  switch (job) {
    case 0: gemm_body(1, 0, GH, DA, 4, DA, -1, -1, 3, 0, 5 * GH, 0, 0, bx, by); break;
    case 1: gemm_body(0, 0, GH, D, 0, D, 0, -1, S, 0, 0, 1, 0, bx, by); break;
    case 2: gemm_body(0, 1 * GH * D, GH, D, 0, D, 1, 2, NACT, 0, GH, 2, 0, bx, by); break;
    case 3: gemm_body(0, 2 * GH * D, GH, D, 0, D, 3, 4, NACT, 0, 2 * GH, 2, 0, bx, by); break;
    case 4: gemm_body(0, 3 * GH * D, GH, D, 0, D, 7, 8, NACT, 0, 3 * GH, 3, 0, bx, by); break;
    case 5: gemm_body(0, 4 * GH * D, GH, D, 0, D, 7, 8, NACT, 0, 4 * GH, 6, 0, bx, by); break;
  }
}

// ---------------------------------------------------------------------------
// Entity epilogue: fwd (g_E) and bwd (g_E2) gates + relation emb, one pass.
__global__ void k_entityAB() {
  int r = blockIdx.x;
  if (g_cide[r] < 0) return;
  int j = threadIdx.x;  // 512
  const float* z = g_E + (size_t)r * GH;
  float c2 = sigm_f(z[j + 512]) * g_c0[j] + sigm_f(z[j]) * tanh_f(z[j + 1024]);
  g_Bent[(size_t)r * 1152 + j] = sigm_f(z[j + 1536]) * tanh_f(c2);
  const float* z2 = g_E2 + (size_t)r * GH;
  float c2b = sigm_f(z2[j + 512]) * g_c0[j] + sigm_f(z2[j]) * tanh_f(z2[j + 1024]);
  g_Bent[(size_t)r * 1152 + 512 + j] = sigm_f(z2[j + 1536]) * tanh_f(c2b);
  if (j < DA) g_Bent[(size_t)r * 1152 + 1024 + j] = g_remb[g_redact[r] * DA + j];
}

// ---------------------------------------------------------------------------
// MULTI-WORKGROUP chains with DATA-AS-SIGNAL (canary) sync.
//
// R5-validated protocol. This round's changes (protocol untouched):
//  - h staging is WAVE-LOCAL (wave c == k-chunk c polls/writes/reads exactly
//    floats [64c,64c+64) of hsh) -> the first barrier is replaced by a
//    wave-level lgkmcnt drain + sched fence.
//  - psh double-buffered by step parity -> ONE __syncthreads per step.
//    WAR safety: step s+2's psh[s&1] writes happen after B(s+1), which wave0
//    passes only after finishing its step-s psh reads (program order).
//  - running cell state in registers (gate lanes only), fast-math gates.
__global__ __launch_bounds__(512, 1) void k_chain_mw(
    const int* __restrict__ acts,
    const void* __restrict__ Whh5raw, const void* __restrict__ WhhAraw,
    int S, int NACT) {
  const int bid = blockIdx.x;
  const int chain = bid & 3;                   // 0..3
  const int wslot = bid >> 2;                  // 0..15
  const int j0 = wslot * 32;
  const int t = threadIdx.x;                   // 0..511
  const int chunk = t >> 6;                    // 0..7 == wave id == k-chunk
  const int rl = t & 63;
  const int m0 = (rl >> 5) * 512 + j0 + (rl & 31);   // gates 0-1
  const int m1 = m0 + 1024;                          // gates 2-3
  const int kb = chunk * 64;

  float* outH; int nsteps;
  if (chain == 0)      { outH = g_Hbuf + H; nsteps = S; }
  else if (chain == 1) { outH = g_Sh;       nsteps = g_counts[0]; }
  else if (chain == 2) { outH = g_Hos;      nsteps = g_counts[1]; }
  else                 { outH = g_Has;      nsteps = NACT; }
  if (nsteps > NFIX) nsteps = NFIX;

  // ---- one-time: weight slices -> registers (raw dtype) ----
  float4 wv0[16], wv1[16];
  if (g_dtype) {
    const ushort_t* base = (chain < 3) ? (const ushort_t*)Whh5raw + (size_t)chain * GH * H
                                       : (const ushort_t*)WhhAraw;
    const ushort_t* p0 = base + (size_t)m0 * H + kb;
    const ushort_t* p1 = base + (size_t)m1 * H + kb;
#pragma unroll
    for (int i = 0; i < 16; i++) {
      ushort4 u0 = *(const ushort4*)(p0 + 4 * i);
      ushort4 u1 = *(const ushort4*)(p1 + 4 * i);
      wv0[i].x = b2f(u0.x); wv0[i].y = b2f(u0.y); wv0[i].z = b2f(u0.z); wv0[i].w = b2f(u0.w);
      wv1[i].x = b2f(u1.x); wv1[i].y = b2f(u1.y); wv1[i].z = b2f(u1.z); wv1[i].w = b2f(u1.w);
    }
  } else {
    const float* base = (chain < 3) ? (const float*)Whh5raw + (size_t)chain * GH * H
                                    : (const float*)WhhAraw;
    const float* p0 = base + (size_t)m0 * H + kb;
    const float* p1 = base + (size_t)m1 * H + kb;
#pragma unroll
    for (int i = 0; i < 16; i++) {
      wv0[i] = *(const float4*)(p0 + 4 * i);
      wv1[i] = *(const float4*)(p1 + 4 * i);
    }
  }

  __shared__ float4 hsh4[128];       // prev hidden state (512 floats)
  __shared__ float  psh[2][8][128];  // chunk partials, step-parity ping-pong
  float creg = 0.f;                  // running cell state (gate lanes, chains != 1)
  if (chain != 1 && t < 32) creg = g_c0[j0 + t];

  for (int s = 0; s < nsteps; s++) {
    // x input row (precomputed, read-only, cached loads) — before the poll
    const float* xrow;
    if (chain == 0)      xrow = g_XB + (size_t)s * GH;
    else if (chain == 1) { int mm = g_map_s[s]; if (mm < 0) mm = 0; if (mm >= NFIX) mm = NFIX - 1;
                           xrow = g_Xso + (size_t)mm * GH; }
    else if (chain == 2) { int mm = g_map_o[s]; if (mm < 0) mm = 0; if (mm >= NFIX) mm = NFIX - 1;
                           xrow = g_Xso + (size_t)mm * GH; }
    else                 { int a = acts[s]; if (a < 0) a = 0; if (a > 2) a = 2;
                           xrow = g_Pa + (size_t)a * GH; }
    float xv0 = 0.f, xv1 = 0.f;
    if (chunk == 0) { xv0 = xrow[m0]; xv1 = xrow[m1]; }

    // previous hidden state source
    int pval = -1;
    const float* hp;
    if (chain == 1) {
      int p = g_par[s]; if (p >= NFIX) p = NFIX - 1;
      pval = p;
      hp = (p == -1) ? g_h0 : ((p < -1) ? nullptr : g_Sh + (size_t)p * H);
    } else {
      hp = (s == 0) ? g_h0 : outH + (size_t)(s - 1) * H;
    }
    const bool h_local = (chain != 1) ? (s == 0) : (pval == -1);  // g_h0: plain read

    // ---- canary-poll own slice: wave-local staging, no barrier ----
    {
      float v;
      if (h_local)          v = hp[t];
      else if (hp == nullptr) v = 0.f;
      else                  v = poll_f(hp + t);
      ((float*)hsh4)[t] = v;
    }
    // wave-level drain: this wave's LDS writes complete before its reads
    asm volatile("s_waitcnt lgkmcnt(0)" ::: "memory");
    __builtin_amdgcn_sched_barrier(0);

    // matvec: one wave-uniform LDS broadcast read feeds 8 FMAs
    float4 a0 = make_float4(0.f, 0.f, 0.f, 0.f);
    float4 a1 = make_float4(0.f, 0.f, 0.f, 0.f);
#pragma unroll
    for (int i = 0; i < 16; i++) {
      float4 hv = hsh4[(chunk << 4) + i];
      a0.x = fmaf(wv0[i].x, hv.x, a0.x);
      a0.y = fmaf(wv0[i].y, hv.y, a0.y);
      a0.z = fmaf(wv0[i].z, hv.z, a0.z);
      a0.w = fmaf(wv0[i].w, hv.w, a0.w);
      a1.x = fmaf(wv1[i].x, hv.x, a1.x);
      a1.y = fmaf(wv1[i].y, hv.y, a1.y);
      a1.z = fmaf(wv1[i].z, hv.z, a1.z);
      a1.w = fmaf(wv1[i].w, hv.w, a1.w);
    }
    float pp0 = (a0.x + a0.y) + (a0.z + a0.w);
    float pp1 = (a1.x + a1.y) + (a1.z + a1.w);
    if (chunk == 0) { pp0 += xv0; pp1 += xv1; }
    const int pp = s & 1;
    psh[pp][chunk][rl] = pp0;
    psh[pp][chunk][rl + 64] = pp1;
    __syncthreads();   // single barrier: partials ready for gate lanes

    // gates + state update + slice store (lanes 0..31 of wave 0)
    if (t < 32) {
      float zi = 0.f, zf = 0.f, zg = 0.f, zo = 0.f;
#pragma unroll
      for (int c = 0; c < 8; c++) {
        zi += psh[pp][c][t];
        zf += psh[pp][c][32 + t];
        zg += psh[pp][c][64 + t];
        zo += psh[pp][c][96 + t];
      }
      float i_ = sigm_f(zi);
      float f_ = sigm_f(zf);
      float o_ = sigm_f(zo);
      int j = j0 + t;
      float cprev;
      if (chain == 1) {
        if (pval == -1)      cprev = g_c0[j];
        else if (pval < -1)  cprev = 0.f;
        else                 cprev = poll_f(&g_Sc[(size_t)pval * H + j]);
      } else {
        cprev = creg;
      }
      float c2 = f_ * cprev + i_ * tanh_f(zg);
      float hn = o_ * tanh_f(c2);
      if (chain == 1) sta_f(&g_Sc[(size_t)s * H + j], c2);
      else            creg = c2;
      sta_f(&outH[(size_t)s * H + j], hn);
      // no drain, no tag: the store replacing the canary IS the publish
    }
  }
}

// ---------------------------------------------------------------------------
__global__ void k_feat() {
  int t = blockIdx.x;
  int j = threadIdx.x;  // 512
  float* f = g_feat + (size_t)t * GH;
  int s = g_stksrc[t]; if (s >= NFIX) s = NFIX - 1;
  f[j] = (s == -1) ? g_empty[j] : ((s < 0) ? 0.f : g_Sh[(size_t)s * H + j]);
  int p = g_bufp[t]; if (p > SFIX) p = SFIX;
  f[H + j] = (p > 0) ? g_Hbuf[(size_t)p * H + j] : g_empty[j];
  int k = g_outsrc[t]; if (k > NFIX) k = NFIX;
  f[2 * H + j] = (k > 0) ? g_Hos[(size_t)(k - 1) * H + j] : g_empty[j];
  f[3 * H + j] = (t > 0) ? g_Has[(size_t)(t - 1) * H + j] : g_empty[j];
}

// ---------------------------------------------------------------------------
__global__ void k_final(const int* __restrict__ actions, void* __restrict__ out) {
  int t = blockIdx.x;
  int lane = threadIdx.x;  // 64
  const float* tv = g_t1 + (size_t)t * H;
  float a0 = 0.f, a1 = 0.f, a2 = 0.f;
  for (int j = lane; j < H; j += 64) {
    float v = tv[j];
    a0 += g_W2[j] * v; a1 += g_W2[H + j] * v; a2 += g_W2[2 * H + j] * v;
  }
  for (int off = 32; off; off >>= 1) {
    a0 += __shfl_down(a0, off);
    a1 += __shfl_down(a1, off);
    a2 += __shfl_down(a2, off);
  }
  if (lane == 0) {
    a0 += g_b2[0]; a1 += g_b2[1]; a2 += g_b2[2];
    float m = fmaxf(a0, fmaxf(a1, a2));
    float lse = m + logf(expf(a0 - m) + expf(a1 - m) + expf(a2 - m));
    int a = actions[t];
    float la = (a <= 0) ? a0 : ((a == 1) ? a1 : a2);
    float v = lse - la;
    if (g_dtype) {
      unsigned int b = __float_as_uint(v);
      b += 0x7FFFu + ((b >> 16) & 1u);     // RNE to bf16
      ((ushort_t*)out)[t] = (ushort_t)(b >> 16);
    } else {
      ((float*)out)[t] = v;
    }
  }
}

// ---------------------------------------------------------------------------
extern "C" void kernel_launch(void* const* d_in, const int* in_sizes, int n_in,
                              void* d_out, int out_size, void* d_ws, size_t ws_size,
                              hipStream_t stream) {
  const int* sent   = (const int*)d_in[0];
  const int* actions= (const int*)d_in[1];
  const void* wemb  = d_in[2];
  const void* aemb  = d_in[3];
  const void* remb  = d_in[4];
  const void* empty = d_in[5];
  const void* h0    = d_in[6];
  const void* c0    = d_in[7];
  const void* Wih5  = d_in[8];
  const void* Whh5  = d_in[9];
  const void* bih5  = d_in[10];
  const void* bhh5  = d_in[11];
  const void* Wih_a = d_in[12];
  const void* Whh_a = d_in[13];
  const void* bih_a = d_in[14];
  const void* bhh_a = d_in[15];
  const void* W1    = d_in[16];
  const void* b1    = d_in[17];
  const void* W2    = d_in[18];
  const void* b2    = d_in[19];
  const void* We    = d_in[20];
  const void* be    = d_in[21];
  int S = in_sizes[0];    // 512
  int NACT = in_sizes[1]; // 768
  if (S > SFIX) S = SFIX;
  if (NACT > NFIX) NACT = NFIX;
  (void)n_in; (void)out_size; (void)d_ws; (void)ws_size;

  k_detect<<<1, 256, 0, stream>>>(h0);
  k_poison<<<1024, 256, 0, stream>>>();   // re-arm canaries every launch

  auto conv = [&](const void* src, int dsel, int n) {
    int blocks = (n + 255) / 256; if (blocks > 1024) blocks = 1024;
    k_b2f<<<blocks, 256, 0, stream>>>(src, dsel, n);
  };
  conv(Wih5, 0, 5 * GH * D);
  conv(Wih_a, 1, GH * DA);
  conv(W1, 2, H * GH);
  conv(We, 3, H * (2 * H + DA));
  conv(W2, 4, 3 * H);
  conv(aemb, 5, 3 * DA);
  conv(remb, 6, 3 * DA);
  conv(empty, 7, H);
  conv(h0, 8, H);
  conv(c0, 9, H);
  conv(b1, 10, H);
  conv(be, 11, D);
  conv(b2, 12, 3);
  conv(bih5, 13, 5 * GH);
  conv(bhh5, 14, 5 * GH);
  conv(bih_a, 15, GH);
  conv(bhh_a, 16, GH);

  k_makewe<<<S, 256, 0, stream>>>(sent, wemb, S);
  k_traj<<<1, 64, 0, stream>>>(actions, NACT, S);
  k_cbias<<<(6 * GH + 255) / 256, 256, 0, stream>>>(Whh5);

  // Stage 1: six independent GEMMs in ONE dispatch (Pa, XB, SHIFT, OUT,
  // E-fwd -> g_E, E-bwd -> g_E2).
  int gyS = (S + 63) / 64, gyN = (NACT + 63) / 64;
  int o1 = 32;
  int o2 = o1 + 32 * gyS;
  int o3 = o2 + 32 * gyN;
  int o4 = o3 + 32 * gyN;
  int o5 = o4 + 32 * gyN;
  int total = o5 + 32 * gyN;
  k_gemm_mega<<<total, 256, 0, stream>>>(o1, o2, o3, o4, o5, S, NACT);
  // entity fwd+bwd gates + relation emb -> Bent
  k_entityAB<<<NACT, 512, 0, stream>>>();

  dim3 gN(GH / 64, gyN);
  dim3 gH(H / 64, gyN);
  // ent = tanh(We @ Bent + be)
  k_gemm<<<gH, 256, 0, stream>>>(2, 0, H, 2 * H + DA, 2, 1152, -1, 8, NACT, 1, 0, 4, 1);
  // Xso[t] REDUCE: Wih2 @ ent[r] + cb2
  k_gemm<<<gN, 256, 0, stream>>>(0, 2 * GH * D, GH, D, 1, H, 5, 6, NACT, 0, 2 * GH, 2, 0);
  // Four LSTM recurrences: 16 WGs each, canary data-as-signal sync.
  k_chain_mw<<<64, 512, 0, stream>>>(actions, Whh5, Whh_a, S, NACT);
  k_feat<<<NACT, 512, 0, stream>>>();
  // t1 = tanh(W1 @ feat + b1)
  k_gemm<<<gH, 256, 0, stream>>>(3, 0, H, GH, 3, GH, -1, -1, NACT, 2, 0, 5, 1);
  k_final<<<NACT, 64, 0, stream>>>(actions, d_out);
}